// Round 1
// baseline (689.972 us; speedup 1.0000x reference)
//
#include <hip/hip_runtime.h>
#include <math.h>

#define B_ 2
#define L_ 1024
#define D_ 1024
#define H_ 16
#define DH_ 64
#define M_ 64
#define R_ 129   // 2*M+1

// ------------------------------------------------------------------
// GEMM: C[2048,1024] = A[2048,1024] @ W[1024,1024] * scale   (fp32)
// tile 64(M) x 128(N), K-step 32, 256 threads, 4x8 micro-tile
// ------------------------------------------------------------------
#define GTM 64
#define GTN 128
#define GTK 32

__global__ __launch_bounds__(256)
void gemm_f32(const float* __restrict__ A, const float* __restrict__ W,
              float* __restrict__ C, float scale)
{
    __shared__ float As[GTK][GTM + 1];   // [k][m], pad to 65 (bank-spread)
    __shared__ float Bs[GTK][GTN];       // [k][n]

    const int t  = threadIdx.x;
    const int tx = t & 15;     // n group: n = tx*8
    const int ty = t >> 4;     // m group: m = ty*4
    const int n0 = blockIdx.x * GTN;
    const int m0 = blockIdx.y * GTM;

    float c[4][8];
#pragma unroll
    for (int i = 0; i < 4; ++i)
#pragma unroll
        for (int j = 0; j < 8; ++j) c[i][j] = 0.f;

    for (int k0 = 0; k0 < D_; k0 += GTK) {
        __syncthreads();
        // stage A tile 64m x 32k (transposed into As[k][m])
        {
            const int kq = (t & 7) * 4;   // 0..28
            const int m  = t >> 3;        // 0..31
#pragma unroll
            for (int it = 0; it < 2; ++it) {
                const int mm = m + it * 32;
                float4 v = *(const float4*)&A[(size_t)(m0 + mm) * D_ + k0 + kq];
                As[kq + 0][mm] = v.x;
                As[kq + 1][mm] = v.y;
                As[kq + 2][mm] = v.z;
                As[kq + 3][mm] = v.w;
            }
        }
        // stage B tile 32k x 128n
        {
            const int n  = (t & 31) * 4;  // 0..124
            const int kk = t >> 5;        // 0..7
#pragma unroll
            for (int it = 0; it < 4; ++it) {
                const int kkk = kk + it * 8;
                float4 v = *(const float4*)&W[(size_t)(k0 + kkk) * D_ + n0 + n];
                *(float4*)&Bs[kkk][n] = v;
            }
        }
        __syncthreads();
#pragma unroll
        for (int kk = 0; kk < GTK; ++kk) {
            float av[4];
#pragma unroll
            for (int mr = 0; mr < 4; ++mr) av[mr] = As[kk][ty * 4 + mr];
            float4 b0 = *(const float4*)&Bs[kk][tx * 8];
            float4 b1 = *(const float4*)&Bs[kk][tx * 8 + 4];
            float bv[8] = {b0.x, b0.y, b0.z, b0.w, b1.x, b1.y, b1.z, b1.w};
#pragma unroll
            for (int mr = 0; mr < 4; ++mr)
#pragma unroll
                for (int nc = 0; nc < 8; ++nc) c[mr][nc] += av[mr] * bv[nc];
        }
    }
#pragma unroll
    for (int mr = 0; mr < 4; ++mr) {
        const size_t row = (size_t)(m0 + ty * 4 + mr) * D_ + n0 + tx * 8;
        float4 o0 = make_float4(c[mr][0] * scale, c[mr][1] * scale,
                                c[mr][2] * scale, c[mr][3] * scale);
        float4 o1 = make_float4(c[mr][4] * scale, c[mr][5] * scale,
                                c[mr][6] * scale, c[mr][7] * scale);
        *(float4*)&C[row]     = o0;
        *(float4*)&C[row + 4] = o1;
    }
}

// ------------------------------------------------------------------
// Flash attention with Shaw relative K/V bias.
// block = 256 thr = 32 q-rows x 8 lanes; KV tiles of 64; 16 tiles.
// grid: (L/32 row-blocks, B*H)
// ------------------------------------------------------------------
#define AROWS 32
#define ATILE 64
#define KPAD  (DH_ + 4)   // 68: rows 16B-aligned, bank-spread
#define RPAD  (R_ + 3)    // 132

__global__ __launch_bounds__(256)
void attn_rel(const float* __restrict__ Q, const float* __restrict__ K,
              const float* __restrict__ V, const float* __restrict__ relk,
              const float* __restrict__ relv, float* __restrict__ O)
{
    __shared__ float Ks[ATILE][KPAD];
    __shared__ float Vs[ATILE][KPAD];     // also used as q staging in phase 0
    __shared__ float Ssh[AROWS][KPAD];    // p tile
    __shared__ float QRs[AROWS][RPAD];    // q . rel_k_table[r]
    __shared__ float wsum[AROWS][RPAD];   // per-offset weight sums

    const int t  = threadIdx.x;
    const int iq = t >> 3;   // 0..31 row in block
    const int q8 = t & 7;    // lane in row-group
    const int ib = blockIdx.x;
    const int bh = blockIdx.y;
    const int b  = bh >> 4;
    const int h  = bh & 15;
    const int ig = ib * AROWS + iq;

    const size_t head_off = (size_t)b * L_ * D_ + (size_t)h * DH_;

    // ---- phase 0: stage q rows into Vs, zero wsum ----
    {
        const int r  = t >> 3;          // 0..31
        const int dq = (t & 7) * 8;     // 0..56
        const float* src = &Q[head_off + (size_t)(ib * AROWS + r) * D_ + dq];
        float4 v0 = *(const float4*)src;
        float4 v1 = *(const float4*)(src + 4);
        *(float4*)&Vs[r][dq]     = v0;
        *(float4*)&Vs[r][dq + 4] = v1;
    }
    {
        float* wp = &wsum[0][0];
        for (int idx = t; idx < AROWS * RPAD; idx += 256) wp[idx] = 0.f;
    }
    __syncthreads();

    // ---- QRs[i][r] = sum_d q[i][d] * relk[r][d] ----
    for (int idx = t; idx < AROWS * R_; idx += 256) {
        const int i = idx / R_;
        const int r = idx - i * R_;
        const float* rk = &relk[r * DH_];
        float acc = 0.f;
#pragma unroll 8
        for (int d = 0; d < DH_; ++d) acc += Vs[i][d] * rk[d];
        QRs[i][r] = acc;
    }

    // ---- own q row into registers ----
    float qreg[DH_];
#pragma unroll
    for (int d4 = 0; d4 < DH_ / 4; ++d4) {
        float4 v = *(const float4*)&Vs[iq][d4 * 4];
        qreg[d4 * 4 + 0] = v.x; qreg[d4 * 4 + 1] = v.y;
        qreg[d4 * 4 + 2] = v.z; qreg[d4 * 4 + 3] = v.w;
    }

    float o[8];
#pragma unroll
    for (int dd = 0; dd < 8; ++dd) o[dd] = 0.f;
    float mrow = -INFINITY, lrow = 0.f;

    const float* Kbase = K + head_off;
    const float* Vbase = V + head_off;

    for (int jt = 0; jt < L_ / ATILE; ++jt) {
        __syncthreads();   // protect Vs/Ks from prior readers (incl. phase 0)
        // ---- stage K,V tile (64 rows x 64) ----
        {
            const int jr = t >> 2;
            const int c0 = (t & 3) * 4;
            const float* ksrc = Kbase + (size_t)(jt * ATILE + jr) * D_;
            const float* vsrc = Vbase + (size_t)(jt * ATILE + jr) * D_;
#pragma unroll
            for (int it = 0; it < 4; ++it) {
                const int d0 = c0 + it * 16;
                *(float4*)&Ks[jr][d0] = *(const float4*)(ksrc + d0);
                *(float4*)&Vs[jr][d0] = *(const float4*)(vsrc + d0);
            }
        }
        __syncthreads();

        // ---- S = q @ K^T + rel bias; columns j = jj*8 + q8 ----
        float p[8];
        float tm = -INFINITY;
#pragma unroll
        for (int jj = 0; jj < 8; ++jj) {
            const int j = jj * 8 + q8;
            const float* kr = &Ks[j][0];
            float acc = 0.f;
#pragma unroll
            for (int d4 = 0; d4 < DH_ / 4; ++d4) {
                float4 kv = *(const float4*)&kr[d4 * 4];
                acc += qreg[d4 * 4 + 0] * kv.x + qreg[d4 * 4 + 1] * kv.y
                     + qreg[d4 * 4 + 2] * kv.z + qreg[d4 * 4 + 3] * kv.w;
            }
            const int jg  = jt * ATILE + j;
            const int rel = jg - ig;
            const int r   = rel < -M_ ? 0 : (rel > M_ ? 2 * M_ : rel + M_);
            p[jj] = acc + QRs[iq][r];
            tm = fmaxf(tm, p[jj]);
        }
        // row max across 8-lane group
        tm = fmaxf(tm, __shfl_xor(tm, 1));
        tm = fmaxf(tm, __shfl_xor(tm, 2));
        tm = fmaxf(tm, __shfl_xor(tm, 4));
        const float newm  = fmaxf(mrow, tm);
        const float rescl = __expf(mrow - newm);   // 0 on first tile
        float tsum = 0.f;
#pragma unroll
        for (int jj = 0; jj < 8; ++jj) {
            p[jj] = __expf(p[jj] - newm);
            tsum += p[jj];
        }
        tsum += __shfl_xor(tsum, 1);
        tsum += __shfl_xor(tsum, 2);
        tsum += __shfl_xor(tsum, 4);
        lrow = lrow * rescl + tsum;
        mrow = newm;
#pragma unroll
        for (int dd = 0; dd < 8; ++dd) o[dd] *= rescl;
        if (rescl != 1.f) {
            for (int r = q8; r < R_; r += 8) wsum[iq][r] *= rescl;
        }
#pragma unroll
        for (int jj = 0; jj < 8; ++jj) Ssh[iq][jj * 8 + q8] = p[jj];
        __syncthreads();   // order rescale-writes before band adds; publish Ssh

        // ---- band / boundary accumulation of wsum ----
        float pe0 = 0.f, pe128 = 0.f;
#pragma unroll
        for (int jj = 0; jj < 8; ++jj) {
            const int jg  = jt * ATILE + jj * 8 + q8;
            const int rel = jg - ig;
            if (rel <= -M_)      pe0   += p[jj];
            else if (rel >= M_)  pe128 += p[jj];
            else                 wsum[iq][rel + M_] += p[jj];  // unique slot per lane
        }
        pe0   += __shfl_xor(pe0, 1);   pe0   += __shfl_xor(pe0, 2);   pe0   += __shfl_xor(pe0, 4);
        pe128 += __shfl_xor(pe128, 1); pe128 += __shfl_xor(pe128, 2); pe128 += __shfl_xor(pe128, 4);
        if (q8 == 0) {
            wsum[iq][0]      += pe0;
            wsum[iq][2 * M_] += pe128;
        }

        // ---- PV: o[dd] += sum_j p[i][j] * V[j][q8*8+dd] ----
#pragma unroll 8
        for (int j = 0; j < ATILE; ++j) {
            const float pj = Ssh[iq][j];
            float4 v0 = *(const float4*)&Vs[j][q8 * 8];
            float4 v1 = *(const float4*)&Vs[j][q8 * 8 + 4];
            o[0] += pj * v0.x; o[1] += pj * v0.y; o[2] += pj * v0.z; o[3] += pj * v0.w;
            o[4] += pj * v1.x; o[5] += pj * v1.y; o[6] += pj * v1.z; o[7] += pj * v1.w;
        }
    }
    __syncthreads();

    // ---- o_rel = wsum @ rel_v_table ----
    float orl[8];
#pragma unroll
    for (int dd = 0; dd < 8; ++dd) orl[dd] = 0.f;
    for (int r = 0; r < R_; ++r) {
        const float wv = wsum[iq][r];
        const float* rv = &relv[r * DH_ + q8 * 8];
        float4 v0 = *(const float4*)rv;
        float4 v1 = *(const float4*)(rv + 4);
        orl[0] += wv * v0.x; orl[1] += wv * v0.y; orl[2] += wv * v0.z; orl[3] += wv * v0.w;
        orl[4] += wv * v1.x; orl[5] += wv * v1.y; orl[6] += wv * v1.z; orl[7] += wv * v1.w;
    }

    const float inv = 1.f / lrow;
    float4 out0 = make_float4((o[0] + orl[0]) * inv, (o[1] + orl[1]) * inv,
                              (o[2] + orl[2]) * inv, (o[3] + orl[3]) * inv);
    float4 out1 = make_float4((o[4] + orl[4]) * inv, (o[5] + orl[5]) * inv,
                              (o[6] + orl[6]) * inv, (o[7] + orl[7]) * inv);
    float* dst = O + head_off + (size_t)ig * D_ + q8 * 8;
    *(float4*)dst       = out0;
    *(float4*)(dst + 4) = out1;
}

// ------------------------------------------------------------------
extern "C" void kernel_launch(void* const* d_in, const int* in_sizes, int n_in,
                              void* d_out, int out_size, void* d_ws, size_t ws_size,
                              hipStream_t stream)
{
    const float* x    = (const float*)d_in[0];
    const float* Wq   = (const float*)d_in[1];
    const float* Wk   = (const float*)d_in[2];
    const float* Wv   = (const float*)d_in[3];
    const float* Wo   = (const float*)d_in[4];
    const float* relk = (const float*)d_in[5];
    const float* relv = (const float*)d_in[6];
    float* out = (float*)d_out;

    const size_t NLD = (size_t)B_ * L_ * D_;   // 2,097,152
    float* Qf = (float*)d_ws;
    float* Kf = Qf + NLD;
    float* Vf = Kf + NLD;
    float* Of = Vf + NLD;

    dim3 gg(D_ / GTN, (B_ * L_) / GTM);        // 8 x 32
    gemm_f32<<<gg, 256, 0, stream>>>(x, Wq, Qf, 0.125f);  // DH^-0.5
    gemm_f32<<<gg, 256, 0, stream>>>(x, Wk, Kf, 1.f);
    gemm_f32<<<gg, 256, 0, stream>>>(x, Wv, Vf, 1.f);

    attn_rel<<<dim3(L_ / AROWS, B_ * H_), 256, 0, stream>>>(Qf, Kf, Vf, relk, relv, Of);

    gemm_f32<<<gg, 256, 0, stream>>>(Of, Wo, out, 1.f);
}

// Round 2
// 429.924 us; speedup vs baseline: 1.6049x; 1.6049x over previous
//
#include <hip/hip_runtime.h>
#include <hip/hip_bf16.h>
#include <math.h>

#define B_ 2
#define L_ 1024
#define D_ 1024
#define H_ 16
#define DH_ 64
#define M_ 64
#define R_ 129   // 2*M+1

using bf16x8 = __attribute__((ext_vector_type(8))) short;
using f32x4  = __attribute__((ext_vector_type(4))) float;

__device__ inline unsigned short f2bf(float f) {
    unsigned int x = __builtin_bit_cast(unsigned int, f);
    unsigned int r = x + 0x7fffu + ((x >> 16) & 1u);   // round-to-nearest-even
    return (unsigned short)(r >> 16);
}

// ------------------------------------------------------------------
// fp32 -> bf16, 4 elems/thread
// ------------------------------------------------------------------
__global__ __launch_bounds__(256)
void f32_to_bf16(const float* __restrict__ in, unsigned short* __restrict__ out, int n4)
{
    int i = blockIdx.x * 256 + threadIdx.x;
    if (i < n4) {
        float4 v = ((const float4*)in)[i];
        short4 o = { (short)f2bf(v.x), (short)f2bf(v.y), (short)f2bf(v.z), (short)f2bf(v.w) };
        ((short4*)out)[i] = o;
    }
}

// ------------------------------------------------------------------
// W[k][n] fp32  ->  Wt[n][k] bf16, four 1024x1024 matrices (z = which)
// 32x32 tiles through LDS, coalesced both sides
// ------------------------------------------------------------------
__global__ __launch_bounds__(256)
void wtranspose(const float* __restrict__ W0, const float* __restrict__ W1,
                const float* __restrict__ W2, const float* __restrict__ W3,
                unsigned short* __restrict__ T0, unsigned short* __restrict__ T1,
                unsigned short* __restrict__ T2, unsigned short* __restrict__ T3)
{
    __shared__ float tile[32][33];
    const int z = blockIdx.z;
    const float* W = z == 0 ? W0 : z == 1 ? W1 : z == 2 ? W2 : W3;
    unsigned short* T = z == 0 ? T0 : z == 1 ? T1 : z == 2 ? T2 : T3;
    const int k0 = blockIdx.y * 32, n0 = blockIdx.x * 32;
    const int t = threadIdx.x;
    const int r = t >> 3;          // 0..31
    const int c = (t & 7) * 4;     // 0..28

    float4 v = *(const float4*)&W[(size_t)(k0 + r) * D_ + n0 + c];
    tile[r][c] = v.x; tile[r][c + 1] = v.y; tile[r][c + 2] = v.z; tile[r][c + 3] = v.w;
    __syncthreads();
    // write row n = n0+r, k = k0+c..c+3  (= tile[c+j][r])
    short4 o = { (short)f2bf(tile[c][r]),     (short)f2bf(tile[c + 1][r]),
                 (short)f2bf(tile[c + 2][r]), (short)f2bf(tile[c + 3][r]) };
    *(short4*)&T[(size_t)(n0 + r) * D_ + k0 + c] = o;
}

// ------------------------------------------------------------------
// C[2048,1024] (fp32) = A[2048,1024](bf16) @ Bt[1024n,1024k](bf16)^T * scale
// 64x64 tile, BK=64, 4 waves, 16x16x32 MFMA, global_load_lds staging,
// XOR-swizzled LDS (swizzle applied on the global SOURCE address; LDS linear).
// ------------------------------------------------------------------
#define BM 64
#define BN 64
#define BK 64

__global__ __launch_bounds__(256)
void gemm_bf16(const unsigned short* __restrict__ A,
               const unsigned short* __restrict__ Bt,
               float* __restrict__ C, float scale)
{
    __shared__ unsigned short As[BM][BK];   // 8 KB, physical layout swizzled
    __shared__ unsigned short Bs[BN][BK];   // 8 KB

    const int t    = threadIdx.x;
    const int lane = t & 63;
    const int wid  = t >> 6;
    const int m0 = blockIdx.y * BM, n0 = blockIdx.x * BN;
    const int wm = (wid >> 1) * 32, wn = (wid & 1) * 32;

    f32x4 acc[2][2] = {};

    // staging map: linear 16B chunk = c*256+t -> row = chunk/8, phys kchunk = chunk%8
    // source k-chunk = phys ^ (row&7)  (involution; read side applies same XOR)
    int srow[2], skof[2], sdst[2];
#pragma unroll
    for (int c = 0; c < 2; ++c) {
        const int chunk = c * 256 + t;
        srow[c] = chunk >> 3;
        skof[c] = ((chunk & 7) ^ (srow[c] & 7)) * 8;
        sdst[c] = chunk * 8;                 // element offset in LDS (linear)
    }

    const int fr   = lane & 15;
    const int kgrp = (lane >> 4) * 8;

    for (int k0 = 0; k0 < D_; k0 += BK) {
        __syncthreads();
#pragma unroll
        for (int c = 0; c < 2; ++c) {
            const unsigned short* ga = A  + (size_t)(m0 + srow[c]) * D_ + k0 + skof[c];
            const unsigned short* gb = Bt + (size_t)(n0 + srow[c]) * D_ + k0 + skof[c];
            __builtin_amdgcn_global_load_lds(
                (const __attribute__((address_space(1))) void*)ga,
                (__attribute__((address_space(3))) void*)(&As[0][0] + sdst[c]), 16, 0, 0);
            __builtin_amdgcn_global_load_lds(
                (const __attribute__((address_space(1))) void*)gb,
                (__attribute__((address_space(3))) void*)(&Bs[0][0] + sdst[c]), 16, 0, 0);
        }
        __syncthreads();

#pragma unroll
        for (int kw = 0; kw < 2; ++kw) {
            bf16x8 av[2], bv[2];
#pragma unroll
            for (int i = 0; i < 2; ++i) {
                const int ra = wm + i * 16 + fr;
                const int ka = (kw * 32 + kgrp) ^ ((ra & 7) * 8);
                av[i] = *(const bf16x8*)&As[ra][ka];
                const int rb = wn + i * 16 + fr;
                const int kb = (kw * 32 + kgrp) ^ ((rb & 7) * 8);
                bv[i] = *(const bf16x8*)&Bs[rb][kb];
            }
#pragma unroll
            for (int i = 0; i < 2; ++i)
#pragma unroll
                for (int j = 0; j < 2; ++j)
                    acc[i][j] = __builtin_amdgcn_mfma_f32_16x16x32_bf16(av[i], bv[j], acc[i][j], 0, 0, 0);
        }
    }

    // epilogue: C/D layout col = lane&15, row = (lane>>4)*4 + reg  [m89-verified]
    const int orow = (lane >> 4) * 4;
#pragma unroll
    for (int i = 0; i < 2; ++i)
#pragma unroll
        for (int j = 0; j < 2; ++j) {
            float* cp = C + (size_t)(m0 + wm + i * 16 + orow) * D_ + n0 + wn + j * 16 + fr;
#pragma unroll
            for (int rg = 0; rg < 4; ++rg)
                cp[(size_t)rg * D_] = acc[i][j][rg] * scale;
        }
}

// ------------------------------------------------------------------
// Flash attention with Shaw relative K/V bias (fp32, unchanged from R1).
// ------------------------------------------------------------------
#define AROWS 32
#define ATILE 64
#define KPAD  (DH_ + 4)
#define RPAD  (R_ + 3)

__global__ __launch_bounds__(256)
void attn_rel(const float* __restrict__ Q, const float* __restrict__ K,
              const float* __restrict__ V, const float* __restrict__ relk,
              const float* __restrict__ relv, float* __restrict__ O)
{
    __shared__ float Ks[ATILE][KPAD];
    __shared__ float Vs[ATILE][KPAD];
    __shared__ float Ssh[AROWS][KPAD];
    __shared__ float QRs[AROWS][RPAD];
    __shared__ float wsum[AROWS][RPAD];

    const int t  = threadIdx.x;
    const int iq = t >> 3;
    const int q8 = t & 7;
    const int ib = blockIdx.x;
    const int bh = blockIdx.y;
    const int b  = bh >> 4;
    const int h  = bh & 15;
    const int ig = ib * AROWS + iq;

    const size_t head_off = (size_t)b * L_ * D_ + (size_t)h * DH_;

    {
        const int r  = t >> 3;
        const int dq = (t & 7) * 8;
        const float* src = &Q[head_off + (size_t)(ib * AROWS + r) * D_ + dq];
        float4 v0 = *(const float4*)src;
        float4 v1 = *(const float4*)(src + 4);
        *(float4*)&Vs[r][dq]     = v0;
        *(float4*)&Vs[r][dq + 4] = v1;
    }
    {
        float* wp = &wsum[0][0];
        for (int idx = t; idx < AROWS * RPAD; idx += 256) wp[idx] = 0.f;
    }
    __syncthreads();

    for (int idx = t; idx < AROWS * R_; idx += 256) {
        const int i = idx / R_;
        const int r = idx - i * R_;
        const float* rk = &relk[r * DH_];
        float acc = 0.f;
#pragma unroll 8
        for (int d = 0; d < DH_; ++d) acc += Vs[i][d] * rk[d];
        QRs[i][r] = acc;
    }

    float qreg[DH_];
#pragma unroll
    for (int d4 = 0; d4 < DH_ / 4; ++d4) {
        float4 v = *(const float4*)&Vs[iq][d4 * 4];
        qreg[d4 * 4 + 0] = v.x; qreg[d4 * 4 + 1] = v.y;
        qreg[d4 * 4 + 2] = v.z; qreg[d4 * 4 + 3] = v.w;
    }

    float o[8];
#pragma unroll
    for (int dd = 0; dd < 8; ++dd) o[dd] = 0.f;
    float mrow = -INFINITY, lrow = 0.f;

    const float* Kbase = K + head_off;
    const float* Vbase = V + head_off;

    for (int jt = 0; jt < L_ / ATILE; ++jt) {
        __syncthreads();
        {
            const int jr = t >> 2;
            const int c0 = (t & 3) * 4;
            const float* ksrc = Kbase + (size_t)(jt * ATILE + jr) * D_;
            const float* vsrc = Vbase + (size_t)(jt * ATILE + jr) * D_;
#pragma unroll
            for (int it = 0; it < 4; ++it) {
                const int d0 = c0 + it * 16;
                *(float4*)&Ks[jr][d0] = *(const float4*)(ksrc + d0);
                *(float4*)&Vs[jr][d0] = *(const float4*)(vsrc + d0);
            }
        }
        __syncthreads();

        float p[8];
        float tm = -INFINITY;
#pragma unroll
        for (int jj = 0; jj < 8; ++jj) {
            const int j = jj * 8 + q8;
            const float* kr = &Ks[j][0];
            float acc = 0.f;
#pragma unroll
            for (int d4 = 0; d4 < DH_ / 4; ++d4) {
                float4 kv = *(const float4*)&kr[d4 * 4];
                acc += qreg[d4 * 4 + 0] * kv.x + qreg[d4 * 4 + 1] * kv.y
                     + qreg[d4 * 4 + 2] * kv.z + qreg[d4 * 4 + 3] * kv.w;
            }
            const int jg  = jt * ATILE + j;
            const int rel = jg - ig;
            const int r   = rel < -M_ ? 0 : (rel > M_ ? 2 * M_ : rel + M_);
            p[jj] = acc + QRs[iq][r];
            tm = fmaxf(tm, p[jj]);
        }
        tm = fmaxf(tm, __shfl_xor(tm, 1));
        tm = fmaxf(tm, __shfl_xor(tm, 2));
        tm = fmaxf(tm, __shfl_xor(tm, 4));
        const float newm  = fmaxf(mrow, tm);
        const float rescl = __expf(mrow - newm);
        float tsum = 0.f;
#pragma unroll
        for (int jj = 0; jj < 8; ++jj) {
            p[jj] = __expf(p[jj] - newm);
            tsum += p[jj];
        }
        tsum += __shfl_xor(tsum, 1);
        tsum += __shfl_xor(tsum, 2);
        tsum += __shfl_xor(tsum, 4);
        lrow = lrow * rescl + tsum;
        mrow = newm;
#pragma unroll
        for (int dd = 0; dd < 8; ++dd) o[dd] *= rescl;
        if (rescl != 1.f) {
            for (int r = q8; r < R_; r += 8) wsum[iq][r] *= rescl;
        }
#pragma unroll
        for (int jj = 0; jj < 8; ++jj) Ssh[iq][jj * 8 + q8] = p[jj];
        __syncthreads();

        float pe0 = 0.f, pe128 = 0.f;
#pragma unroll
        for (int jj = 0; jj < 8; ++jj) {
            const int jg  = jt * ATILE + jj * 8 + q8;
            const int rel = jg - ig;
            if (rel <= -M_)      pe0   += p[jj];
            else if (rel >= M_)  pe128 += p[jj];
            else                 wsum[iq][rel + M_] += p[jj];
        }
        pe0   += __shfl_xor(pe0, 1);   pe0   += __shfl_xor(pe0, 2);   pe0   += __shfl_xor(pe0, 4);
        pe128 += __shfl_xor(pe128, 1); pe128 += __shfl_xor(pe128, 2); pe128 += __shfl_xor(pe128, 4);
        if (q8 == 0) {
            wsum[iq][0]      += pe0;
            wsum[iq][2 * M_] += pe128;
        }

#pragma unroll 8
        for (int j = 0; j < ATILE; ++j) {
            const float pj = Ssh[iq][j];
            float4 v0 = *(const float4*)&Vs[j][q8 * 8];
            float4 v1 = *(const float4*)&Vs[j][q8 * 8 + 4];
            o[0] += pj * v0.x; o[1] += pj * v0.y; o[2] += pj * v0.z; o[3] += pj * v0.w;
            o[4] += pj * v1.x; o[5] += pj * v1.y; o[6] += pj * v1.z; o[7] += pj * v1.w;
        }
    }
    __syncthreads();

    float orl[8];
#pragma unroll
    for (int dd = 0; dd < 8; ++dd) orl[dd] = 0.f;
    for (int r = 0; r < R_; ++r) {
        const float wv = wsum[iq][r];
        const float* rv = &relv[r * DH_ + q8 * 8];
        float4 v0 = *(const float4*)rv;
        float4 v1 = *(const float4*)(rv + 4);
        orl[0] += wv * v0.x; orl[1] += wv * v0.y; orl[2] += wv * v0.z; orl[3] += wv * v0.w;
        orl[4] += wv * v1.x; orl[5] += wv * v1.y; orl[6] += wv * v1.z; orl[7] += wv * v1.w;
    }

    const float inv = 1.f / lrow;
    float4 out0 = make_float4((o[0] + orl[0]) * inv, (o[1] + orl[1]) * inv,
                              (o[2] + orl[2]) * inv, (o[3] + orl[3]) * inv);
    float4 out1 = make_float4((o[4] + orl[4]) * inv, (o[5] + orl[5]) * inv,
                              (o[6] + orl[6]) * inv, (o[7] + orl[7]) * inv);
    float* dst = O + head_off + (size_t)ig * D_ + q8 * 8;
    *(float4*)dst       = out0;
    *(float4*)(dst + 4) = out1;
}

// ------------------------------------------------------------------
extern "C" void kernel_launch(void* const* d_in, const int* in_sizes, int n_in,
                              void* d_out, int out_size, void* d_ws, size_t ws_size,
                              hipStream_t stream)
{
    const float* x    = (const float*)d_in[0];
    const float* Wq   = (const float*)d_in[1];
    const float* Wk   = (const float*)d_in[2];
    const float* Wv   = (const float*)d_in[3];
    const float* Wo   = (const float*)d_in[4];
    const float* relk = (const float*)d_in[5];
    const float* relv = (const float*)d_in[6];
    float* out = (float*)d_out;

    const size_t NLD = (size_t)B_ * L_ * D_;   // 2,097,152
    float* Qf = (float*)d_ws;
    float* Kf = Qf + NLD;
    float* Vf = Kf + NLD;
    float* Of = Vf + NLD;
    unsigned short* xb  = (unsigned short*)(Of + NLD);  // 2M bf16; reused for Of-bf16
    unsigned short* Wtq = xb + NLD;
    unsigned short* Wtk = Wtq + (size_t)D_ * D_;
    unsigned short* Wtv = Wtk + (size_t)D_ * D_;
    unsigned short* Wto = Wtv + (size_t)D_ * D_;

    // x -> bf16
    f32_to_bf16<<<dim3((NLD / 4 + 255) / 256), 256, 0, stream>>>(x, xb, (int)(NLD / 4));
    // W -> Wt (bf16, [n][k]) x4
    wtranspose<<<dim3(32, 32, 4), 256, 0, stream>>>(Wq, Wk, Wv, Wo, Wtq, Wtk, Wtv, Wto);

    dim3 gg(D_ / BN, (B_ * L_) / BM);          // 16 x 32
    gemm_bf16<<<gg, 256, 0, stream>>>(xb, Wtq, Qf, 0.125f);   // DH^-0.5
    gemm_bf16<<<gg, 256, 0, stream>>>(xb, Wtk, Kf, 1.f);
    gemm_bf16<<<gg, 256, 0, stream>>>(xb, Wtv, Vf, 1.f);

    attn_rel<<<dim3(L_ / AROWS, B_ * H_), 256, 0, stream>>>(Qf, Kf, Vf, relk, relv, Of);

    // Of -> bf16 (reuse xb slot), final GEMM into d_out
    f32_to_bf16<<<dim3((NLD / 4 + 255) / 256), 256, 0, stream>>>(Of, xb, (int)(NLD / 4));
    gemm_bf16<<<gg, 256, 0, stream>>>(xb, Wto, out, 1.f);
}

// Round 3
// 110.109 us; speedup vs baseline: 6.2663x; 3.9045x over previous
//
#include <hip/hip_runtime.h>
#include <hip/hip_bf16.h>
#include <math.h>

#define B_ 2
#define L_ 1024
#define D_ 1024
#define H_ 16
#define DH_ 64
#define M_ 64
#define R_ 129   // 2*M+1

using bf16x8 = __attribute__((ext_vector_type(8))) short;
using f32x4  = __attribute__((ext_vector_type(4))) float;

__device__ __forceinline__ unsigned short f2bf(float f) {
    unsigned int x = __builtin_bit_cast(unsigned int, f);
    unsigned int r = x + 0x7fffu + ((x >> 16) & 1u);   // round-to-nearest-even
    return (unsigned short)(r >> 16);
}
__device__ __forceinline__ float bf2f(unsigned short u) {
    unsigned int x = ((unsigned int)u) << 16;
    return __builtin_bit_cast(float, x);
}

// ------------------------------------------------------------------
// fp32 -> bf16, 4 elems/thread
// ------------------------------------------------------------------
__global__ __launch_bounds__(256)
void f32_to_bf16(const float* __restrict__ in, unsigned short* __restrict__ out, int n4)
{
    int i = blockIdx.x * 256 + threadIdx.x;
    if (i < n4) {
        float4 v = ((const float4*)in)[i];
        short4 o = { (short)f2bf(v.x), (short)f2bf(v.y), (short)f2bf(v.z), (short)f2bf(v.w) };
        ((short4*)out)[i] = o;
    }
}

// ------------------------------------------------------------------
// W[k][n] fp32 -> Wt[n][k] bf16, four matrices
// ------------------------------------------------------------------
__global__ __launch_bounds__(256)
void wtranspose(const float* __restrict__ W0, const float* __restrict__ W1,
                const float* __restrict__ W2, const float* __restrict__ W3,
                unsigned short* __restrict__ T0, unsigned short* __restrict__ T1,
                unsigned short* __restrict__ T2, unsigned short* __restrict__ T3)
{
    __shared__ float tile[32][33];
    const int z = blockIdx.z;
    const float* W = z == 0 ? W0 : z == 1 ? W1 : z == 2 ? W2 : W3;
    unsigned short* T = z == 0 ? T0 : z == 1 ? T1 : z == 2 ? T2 : T3;
    const int k0 = blockIdx.y * 32, n0 = blockIdx.x * 32;
    const int t = threadIdx.x;
    const int r = t >> 3;
    const int c = (t & 7) * 4;

    float4 v = *(const float4*)&W[(size_t)(k0 + r) * D_ + n0 + c];
    tile[r][c] = v.x; tile[r][c + 1] = v.y; tile[r][c + 2] = v.z; tile[r][c + 3] = v.w;
    __syncthreads();
    short4 o = { (short)f2bf(tile[c][r]),     (short)f2bf(tile[c + 1][r]),
                 (short)f2bf(tile[c + 2][r]), (short)f2bf(tile[c + 3][r]) };
    *(short4*)&T[(size_t)(n0 + r) * D_ + k0 + c] = o;
}

// ------------------------------------------------------------------
// relkb: [144][64] bf16 (rows >=129 zero); relvT: [64][136] bf16 ([d][r])
// ------------------------------------------------------------------
__global__ __launch_bounds__(256)
void prep_rel(const float* __restrict__ relk, const float* __restrict__ relv,
              unsigned short* __restrict__ relkb, unsigned short* __restrict__ relvT)
{
    int idx = blockIdx.x * 256 + threadIdx.x;
    if (idx < 144 * 64) {
        int r = idx >> 6, d = idx & 63;
        relkb[idx] = (r < R_) ? f2bf(relk[r * 64 + d]) : (unsigned short)0;
    }
    if (idx < 64 * 136) {
        int d = idx / 136, r = idx - d * 136;
        relvT[idx] = (r < R_) ? f2bf(relv[r * 64 + d]) : (unsigned short)0;
    }
}

// ------------------------------------------------------------------
// bf16 MFMA GEMM (unchanged from R2): C = A @ Bt^T * scale
// ------------------------------------------------------------------
#define BM 64
#define BN 64
#define BK 64

__global__ __launch_bounds__(256)
void gemm_bf16(const unsigned short* __restrict__ A,
               const unsigned short* __restrict__ Bt,
               float* __restrict__ C, float scale)
{
    __shared__ unsigned short As[BM][BK];
    __shared__ unsigned short Bs[BN][BK];

    const int t    = threadIdx.x;
    const int lane = t & 63;
    const int wid  = t >> 6;
    const int m0 = blockIdx.y * BM, n0 = blockIdx.x * BN;
    const int wm = (wid >> 1) * 32, wn = (wid & 1) * 32;

    f32x4 acc[2][2] = {};

    int srow[2], skof[2], sdst[2];
#pragma unroll
    for (int c = 0; c < 2; ++c) {
        const int chunk = c * 256 + t;
        srow[c] = chunk >> 3;
        skof[c] = ((chunk & 7) ^ (srow[c] & 7)) * 8;
        sdst[c] = chunk * 8;
    }

    const int fr   = lane & 15;
    const int kgrp = (lane >> 4) * 8;

    for (int k0 = 0; k0 < D_; k0 += BK) {
        __syncthreads();
#pragma unroll
        for (int c = 0; c < 2; ++c) {
            const unsigned short* ga = A  + (size_t)(m0 + srow[c]) * D_ + k0 + skof[c];
            const unsigned short* gb = Bt + (size_t)(n0 + srow[c]) * D_ + k0 + skof[c];
            __builtin_amdgcn_global_load_lds(
                (const __attribute__((address_space(1))) void*)ga,
                (__attribute__((address_space(3))) void*)(&As[0][0] + sdst[c]), 16, 0, 0);
            __builtin_amdgcn_global_load_lds(
                (const __attribute__((address_space(1))) void*)gb,
                (__attribute__((address_space(3))) void*)(&Bs[0][0] + sdst[c]), 16, 0, 0);
        }
        __syncthreads();

#pragma unroll
        for (int kw = 0; kw < 2; ++kw) {
            bf16x8 av[2], bv[2];
#pragma unroll
            for (int i = 0; i < 2; ++i) {
                const int ra = wm + i * 16 + fr;
                const int ka = (kw * 32 + kgrp) ^ ((ra & 7) * 8);
                av[i] = *(const bf16x8*)&As[ra][ka];
                const int rb = wn + i * 16 + fr;
                const int kb = (kw * 32 + kgrp) ^ ((rb & 7) * 8);
                bv[i] = *(const bf16x8*)&Bs[rb][kb];
            }
#pragma unroll
            for (int i = 0; i < 2; ++i)
#pragma unroll
                for (int j = 0; j < 2; ++j)
                    acc[i][j] = __builtin_amdgcn_mfma_f32_16x16x32_bf16(av[i], bv[j], acc[i][j], 0, 0, 0);
        }
    }

    const int orow = (lane >> 4) * 4;
#pragma unroll
    for (int i = 0; i < 2; ++i)
#pragma unroll
        for (int j = 0; j < 2; ++j) {
            float* cp = C + (size_t)(m0 + wm + i * 16 + orow) * D_ + n0 + wn + j * 16 + fr;
#pragma unroll
            for (int rg = 0; rg < 4; ++rg)
                cp[(size_t)rg * D_] = acc[i][j][rg] * scale;
        }
}

// ------------------------------------------------------------------
// MFMA flash attention with Shaw relative K/V bias.
// 512 blocks (16 row-blocks x 32 bh, XCD-chunked), 4 waves x 16 q-rows.
// No online rescale: logits are small (|s|<~3), p=exp(s+bias) accumulated
// raw, normalized once at the end (exp factors cancel exactly).
// ------------------------------------------------------------------
__device__ __forceinline__ void stage_write(unsigned short Kl[][64], unsigned short Vtl[][64], int t,
                                            float4 k0, float4 k1, float4 k2, float4 k3,
                                            float4 v0, float4 v1, float4 v2, float4 v3)
{
    const int sj  = t >> 2;
    const int sd0 = (t & 3) * 16;
    const int sjh = sj >> 3;
    const int sjl = sj & 7;
    // V^T with chunk swizzle: element (d, j) at Vt[d][ ((j>>3)^(d&7))*8 + (j&7) ]
#define VW(E, VAL) Vtl[sd0 + (E)][((sjh ^ ((E) & 7)) << 3) + sjl] = f2bf(VAL)
    VW(0,  v0.x); VW(1,  v0.y); VW(2,  v0.z); VW(3,  v0.w);
    VW(4,  v1.x); VW(5,  v1.y); VW(6,  v1.z); VW(7,  v1.w);
    VW(8,  v2.x); VW(9,  v2.y); VW(10, v2.z); VW(11, v2.w);
    VW(12, v3.x); VW(13, v3.y); VW(14, v3.z); VW(15, v3.w);
#undef VW
    bf16x8 a, c;
    a[0]=(short)f2bf(k0.x); a[1]=(short)f2bf(k0.y); a[2]=(short)f2bf(k0.z); a[3]=(short)f2bf(k0.w);
    a[4]=(short)f2bf(k1.x); a[5]=(short)f2bf(k1.y); a[6]=(short)f2bf(k1.z); a[7]=(short)f2bf(k1.w);
    c[0]=(short)f2bf(k2.x); c[1]=(short)f2bf(k2.y); c[2]=(short)f2bf(k2.z); c[3]=(short)f2bf(k2.w);
    c[4]=(short)f2bf(k3.x); c[5]=(short)f2bf(k3.y); c[6]=(short)f2bf(k3.z); c[7]=(short)f2bf(k3.w);
    const int c0 = (t & 3) * 2;
    *(bf16x8*)&Kl[sj][((c0)     ^ sjl) * 8] = a;
    *(bf16x8*)&Kl[sj][((c0 + 1) ^ sjl) * 8] = c;
}

__global__ __launch_bounds__(256)
void attn_mfma(const float* __restrict__ Q, const float* __restrict__ K,
               const float* __restrict__ V,
               const unsigned short* __restrict__ relkb,   // [144][64] bf16
               const unsigned short* __restrict__ relvT,   // [64][136] bf16
               const float* __restrict__ relv,             // [129][64] f32
               float* __restrict__ O)
{
    __shared__ unsigned short Klds[2][64][64];  // chunk-swizzled
    __shared__ unsigned short Vt[2][64][64];    // V^T, chunk-swizzled
    __shared__ unsigned short Plds[64][72];
    __shared__ unsigned short QRs[64][144];     // q . relk[r], bf16
    __shared__ unsigned short Wsum[64][136];    // per-offset weight sums, bf16

    const int t    = threadIdx.x;
    const int lane = t & 63;
    const int w    = t >> 6;
    const int fr   = lane & 15;
    const int g    = lane >> 4;
    const int rg0  = g * 4;

    // XCD-chunked block swizzle: XCD x owns bh in [4x, 4x+4) (K/V L2-resident)
    const int bx  = blockIdx.x;
    const int xcd = bx & 7, slot = bx >> 3;
    const int bh  = (xcd << 2) | (slot >> 4);
    const int rb  = slot & 15;
    const int b   = bh >> 4, h = bh & 15;
    const int i0  = rb * 64;
    const size_t head = (size_t)b * L_ * D_ + (size_t)h * DH_;

    // zero Wsum
    {
        unsigned int* wp = (unsigned int*)&Wsum[0][0];
        for (int i = t; i < 64 * 136 / 2; i += 256) wp[i] = 0u;
    }

    // Q fragments (A-operand): row = i0 + w*16 + fr, k = kb*32 + g*8 + e
    bf16x8 qf[2];
    {
        const float* qp = Q + head + (size_t)(i0 + w * 16 + fr) * D_ + g * 8;
#pragma unroll
        for (int kb = 0; kb < 2; ++kb) {
            float4 a = *(const float4*)(qp + kb * 32);
            float4 c = *(const float4*)(qp + kb * 32 + 4);
            bf16x8 v;
            v[0]=(short)f2bf(a.x); v[1]=(short)f2bf(a.y); v[2]=(short)f2bf(a.z); v[3]=(short)f2bf(a.w);
            v[4]=(short)f2bf(c.x); v[5]=(short)f2bf(c.y); v[6]=(short)f2bf(c.z); v[7]=(short)f2bf(c.w);
            qf[kb] = v;
        }
    }

    // QR[i][r] = q[i] . relk[r] via MFMA (9 col-frags cover r=0..143, pad zero)
    float qr0[4], qr128[4];
#pragma unroll
    for (int rc = 0; rc < 9; ++rc) {
        f32x4 acc = {};
#pragma unroll
        for (int kb = 0; kb < 2; ++kb) {
            bf16x8 rv = *(const bf16x8*)&relkb[(size_t)(rc * 16 + fr) * 64 + kb * 32 + g * 8];
            acc = __builtin_amdgcn_mfma_f32_16x16x32_bf16(qf[kb], rv, acc, 0, 0, 0);
        }
#pragma unroll
        for (int reg = 0; reg < 4; ++reg)
            QRs[w * 16 + rg0 + reg][rc * 16 + fr] = f2bf(acc[reg]);
        if (rc == 0) {
#pragma unroll
            for (int reg = 0; reg < 4; ++reg) qr0[reg] = __shfl(acc[reg], g * 16, 64);
        }
        if (rc == 8) {
#pragma unroll
            for (int reg = 0; reg < 4; ++reg) qr128[reg] = __shfl(acc[reg], g * 16, 64);
        }
    }

    const int sj = t >> 2, sd0 = (t & 3) * 16;
    const float* Kb = K + head;
    const float* Vb = V + head;

    // stage tile 0
    {
        const float* kp = Kb + (size_t)sj * D_ + sd0;
        const float* vp = Vb + (size_t)sj * D_ + sd0;
        float4 k0 = *(const float4*)kp,       k1 = *(const float4*)(kp + 4);
        float4 k2 = *(const float4*)(kp + 8), k3 = *(const float4*)(kp + 12);
        float4 v0 = *(const float4*)vp,       v1 = *(const float4*)(vp + 4);
        float4 v2 = *(const float4*)(vp + 8), v3 = *(const float4*)(vp + 12);
        stage_write(Klds[0], Vt[0], t, k0, k1, k2, k3, v0, v1, v2, v3);
    }
    __syncthreads();

    f32x4 oacc[4] = {};
    float lpart[4] = {}, pe0p[4] = {}, pe128p[4] = {};

    int bb = 0;
    for (int jt = 0; jt < 16; ++jt) {
        float4 k0, k1, k2, k3, v0, v1, v2, v3;
        const bool pre = (jt < 15);
        if (pre) {
            const float* kp = Kb + (size_t)((jt + 1) * 64 + sj) * D_ + sd0;
            const float* vp = Vb + (size_t)((jt + 1) * 64 + sj) * D_ + sd0;
            k0 = *(const float4*)kp;       k1 = *(const float4*)(kp + 4);
            k2 = *(const float4*)(kp + 8); k3 = *(const float4*)(kp + 12);
            v0 = *(const float4*)vp;       v1 = *(const float4*)(vp + 4);
            v2 = *(const float4*)(vp + 8); v3 = *(const float4*)(vp + 12);
        }

        // ---- S = q @ K^T ----
        f32x4 s[4];
#pragma unroll
        for (int fc = 0; fc < 4; ++fc) {
            f32x4 a = {};
            const int j = fc * 16 + fr;
#pragma unroll
            for (int kb = 0; kb < 2; ++kb) {
                bf16x8 kv = *(const bf16x8*)&Klds[bb][j][(((kb << 2) + g) ^ (j & 7)) * 8];
                a = __builtin_amdgcn_mfma_f32_16x16x32_bf16(qf[kb], kv, a, 0, 0, 0);
            }
            s[fc] = a;
        }

        const int dt = (jt - rb) * 64;   // j0 - i0
        if (dt <= -128 || dt >= 128) {
            // far tile: bias is per-row constant; whole tile is one boundary class
            const bool lo = dt < 0;
#pragma unroll
            for (int reg = 0; reg < 4; ++reg) {
                const float qrc = lo ? qr0[reg] : qr128[reg];
                float rsum = 0.f;
#pragma unroll
                for (int fc = 0; fc < 4; ++fc) {
                    float pe = __expf(s[fc][reg] + qrc);
                    rsum += pe;
                    Plds[w * 16 + rg0 + reg][fc * 16 + fr] = f2bf(pe);
                }
                lpart[reg] += rsum;
                if (lo) pe0p[reg] += rsum; else pe128p[reg] += rsum;
            }
        } else {
            // near-diagonal: per-element bias + interior single-write scatter
#pragma unroll
            for (int fc = 0; fc < 4; ++fc) {
#pragma unroll
                for (int reg = 0; reg < 4; ++reg) {
                    const int li  = w * 16 + rg0 + reg;
                    const int rel = dt + fc * 16 + fr - li;
                    float bias;
                    if (rel <= -M_)     bias = qr0[reg];
                    else if (rel >= M_) bias = qr128[reg];
                    else                bias = bf2f(QRs[li][rel + M_]);
                    float pe = __expf(s[fc][reg] + bias);
                    lpart[reg] += pe;
                    Plds[li][fc * 16 + fr] = f2bf(pe);
                    if (rel <= -M_)      pe0p[reg]   += pe;
                    else if (rel >= M_)  pe128p[reg] += pe;
                    else                 Wsum[li][rel + M_] = f2bf(pe);
                }
            }
        }

        asm volatile("s_waitcnt lgkmcnt(0)" ::: "memory");

        // ---- PV: A = P (rows lane-local), B = V^T ----
        bf16x8 pa0 = *(const bf16x8*)&Plds[w * 16 + fr][g * 8];
        bf16x8 pa1 = *(const bf16x8*)&Plds[w * 16 + fr][32 + g * 8];
#pragma unroll
        for (int fd = 0; fd < 4; ++fd) {
            const int d = fd * 16 + fr;
            bf16x8 vv0 = *(const bf16x8*)&Vt[bb][d][((g)     ^ (d & 7)) * 8];
            bf16x8 vv1 = *(const bf16x8*)&Vt[bb][d][((4 + g) ^ (d & 7)) * 8];
            oacc[fd] = __builtin_amdgcn_mfma_f32_16x16x32_bf16(pa0, vv0, oacc[fd], 0, 0, 0);
            oacc[fd] = __builtin_amdgcn_mfma_f32_16x16x32_bf16(pa1, vv1, oacc[fd], 0, 0, 0);
        }

        if (pre) stage_write(Klds[bb ^ 1], Vt[bb ^ 1], t, k0, k1, k2, k3, v0, v1, v2, v3);
        __syncthreads();
        bb ^= 1;
    }

    // ---- reduce row partials across the 16 fr-lanes ----
#pragma unroll
    for (int m = 1; m <= 8; m <<= 1) {
#pragma unroll
        for (int reg = 0; reg < 4; ++reg) {
            lpart[reg]  += __shfl_xor(lpart[reg],  m, 64);
            pe0p[reg]   += __shfl_xor(pe0p[reg],   m, 64);
            pe128p[reg] += __shfl_xor(pe128p[reg], m, 64);
        }
    }
    if (fr == 0) {
#pragma unroll
        for (int reg = 0; reg < 4; ++reg) {
            Wsum[w * 16 + rg0 + reg][0]   = f2bf(pe0p[reg]);
            Wsum[w * 16 + rg0 + reg][128] = f2bf(pe128p[reg]);
        }
    }
    asm volatile("s_waitcnt lgkmcnt(0)" ::: "memory");
    __syncthreads();

    // ---- o += wsum @ relv  (r=0..127 via MFMA; r=128 scalar) ----
#pragma unroll
    for (int kc = 0; kc < 4; ++kc) {
        bf16x8 wa = *(const bf16x8*)&Wsum[w * 16 + fr][kc * 32 + g * 8];
#pragma unroll
        for (int fd = 0; fd < 4; ++fd) {
            bf16x8 rv = *(const bf16x8*)&relvT[(size_t)(fd * 16 + fr) * 136 + kc * 32 + g * 8];
            oacc[fd] = __builtin_amdgcn_mfma_f32_16x16x32_bf16(wa, rv, oacc[fd], 0, 0, 0);
        }
    }

    float inv[4];
#pragma unroll
    for (int reg = 0; reg < 4; ++reg) inv[reg] = 1.f / lpart[reg];

#pragma unroll
    for (int fd = 0; fd < 4; ++fd) {
        const float r128 = relv[128 * 64 + fd * 16 + fr];
        float* op = O + head + (size_t)(i0 + w * 16 + rg0) * D_ + fd * 16 + fr;
#pragma unroll
        for (int reg = 0; reg < 4; ++reg)
            op[(size_t)reg * D_] = (oacc[fd][reg] + pe128p[reg] * r128) * inv[reg];
    }
}

// ------------------------------------------------------------------
extern "C" void kernel_launch(void* const* d_in, const int* in_sizes, int n_in,
                              void* d_out, int out_size, void* d_ws, size_t ws_size,
                              hipStream_t stream)
{
    const float* x    = (const float*)d_in[0];
    const float* Wq   = (const float*)d_in[1];
    const float* Wk   = (const float*)d_in[2];
    const float* Wv   = (const float*)d_in[3];
    const float* Wo   = (const float*)d_in[4];
    const float* relk = (const float*)d_in[5];
    const float* relv = (const float*)d_in[6];
    float* out = (float*)d_out;

    const size_t NLD = (size_t)B_ * L_ * D_;   // 2,097,152
    const size_t DD  = (size_t)D_ * D_;
    float* Qf = (float*)d_ws;
    float* Kf = Qf + NLD;
    float* Vf = Kf + NLD;
    float* Of = Vf + NLD;
    unsigned short* xb    = (unsigned short*)(Of + NLD);
    unsigned short* Wtq   = xb + NLD;
    unsigned short* Wtk   = Wtq + DD;
    unsigned short* Wtv   = Wtk + DD;
    unsigned short* Wto   = Wtv + DD;
    unsigned short* relkb = Wto + DD;          // 144*64
    unsigned short* relvT = relkb + 144 * 64;  // 64*136

    f32_to_bf16<<<dim3((NLD / 4 + 255) / 256), 256, 0, stream>>>(x, xb, (int)(NLD / 4));
    wtranspose<<<dim3(32, 32, 4), 256, 0, stream>>>(Wq, Wk, Wv, Wo, Wtq, Wtk, Wtv, Wto);
    prep_rel<<<dim3(36), 256, 0, stream>>>(relk, relv, relkb, relvT);

    dim3 gg(D_ / BN, (B_ * L_) / BM);
    gemm_bf16<<<gg, 256, 0, stream>>>(xb, Wtq, Qf, 0.125f);
    gemm_bf16<<<gg, 256, 0, stream>>>(xb, Wtk, Kf, 1.f);
    gemm_bf16<<<gg, 256, 0, stream>>>(xb, Wtv, Vf, 1.f);

    attn_mfma<<<dim3(512), 256, 0, stream>>>(Qf, Kf, Vf, relkb, relvT, relv, Of);

    f32_to_bf16<<<dim3((NLD / 4 + 255) / 256), 256, 0, stream>>>(Of, xb, (int)(NLD / 4));
    gemm_bf16<<<gg, 256, 0, stream>>>(xb, Wto, out, 1.f);
}

// Round 4
// 94.706 us; speedup vs baseline: 7.2854x; 1.1626x over previous
//
#include <hip/hip_runtime.h>
#include <hip/hip_bf16.h>
#include <math.h>

#define B_ 2
#define L_ 1024
#define D_ 1024
#define H_ 16
#define DH_ 64
#define M_ 64
#define R_ 129
#define NLD ((size_t)B_ * L_ * D_)          // 2,097,152
#define DD  ((size_t)D_ * D_)
#define QSCALE 0.18033688011112042f         // DH^-0.5 * log2(e)

using bf16x8 = __attribute__((ext_vector_type(8))) short;
using f32x4  = __attribute__((ext_vector_type(4))) float;

__device__ __forceinline__ unsigned short f2bf(float f) {
    unsigned int x = __builtin_bit_cast(unsigned int, f);
    unsigned int r = x + 0x7fffu + ((x >> 16) & 1u);   // RNE
    return (unsigned short)(r >> 16);
}
__device__ __forceinline__ float bf2f(unsigned short u) {
    unsigned int x = ((unsigned int)u) << 16;
    return __builtin_bit_cast(float, x);
}

// ------------------------------------------------------------------
// prep: [0,2048) x->bf16 | [2048,6144) W transposes | [6144,6180) rel tables
// ------------------------------------------------------------------
__global__ __launch_bounds__(256)
void prep(const float* __restrict__ x,
          const float* __restrict__ W0, const float* __restrict__ W1,
          const float* __restrict__ W2, const float* __restrict__ W3,
          const float* __restrict__ relk, const float* __restrict__ relv,
          unsigned short* __restrict__ xb, unsigned short* __restrict__ Wt,
          unsigned short* __restrict__ relkb, unsigned short* __restrict__ relvT)
{
    __shared__ float tile[32][33];
    const int bid = blockIdx.x, t = threadIdx.x;
    if (bid < 2048) {
        const int i = bid * 256 + t;
        float4 v = ((const float4*)x)[i];
        short4 o = { (short)f2bf(v.x), (short)f2bf(v.y), (short)f2bf(v.z), (short)f2bf(v.w) };
        ((short4*)xb)[i] = o;
    } else if (bid < 6144) {
        const int wb = bid - 2048;
        const int z = wb >> 10, rem = wb & 1023;
        const float* W = z == 0 ? W0 : z == 1 ? W1 : z == 2 ? W2 : W3;
        unsigned short* T = Wt + (size_t)z * DD;
        const int k0 = (rem >> 5) * 32, n0 = (rem & 31) * 32;
        const int r = t >> 3, c = (t & 7) * 4;
        float4 v = *(const float4*)&W[(size_t)(k0 + r) * D_ + n0 + c];
        tile[r][c] = v.x; tile[r][c + 1] = v.y; tile[r][c + 2] = v.z; tile[r][c + 3] = v.w;
        __syncthreads();
        short4 o = { (short)f2bf(tile[c][r]),     (short)f2bf(tile[c + 1][r]),
                     (short)f2bf(tile[c + 2][r]), (short)f2bf(tile[c + 3][r]) };
        *(short4*)&T[(size_t)(n0 + r) * D_ + k0 + c] = o;
    } else {
        const int idx = (bid - 6144) * 256 + t;
        if (idx < 144 * 64) {
            const int r = idx >> 6, d = idx & 63;
            relkb[idx] = (r < R_) ? f2bf(relk[r * 64 + d]) : (unsigned short)0;
        }
        if (idx < 64 * 136) {
            const int d = idx / 136, r = idx - d * 136;
            relvT[idx] = (r < R_) ? f2bf(relv[r * 64 + d]) : (unsigned short)0;
        }
    }
}

// ------------------------------------------------------------------
// 128x128-tile bf16 MFMA GEMM (m97 structure), BK=64, 4 waves x 64x64.
// A [2048][1024] bf16; Bt rows stacked per-matrix ([nmats*1024][1024]).
// Cb != null: bf16 out (per-mat offset, mat0 scaled); else f32 out.
// ------------------------------------------------------------------
__global__ __launch_bounds__(256)
void gemm128(const unsigned short* __restrict__ A, const unsigned short* __restrict__ Bt,
             unsigned short* __restrict__ Cb, float* __restrict__ Cf, float scale0)
{
    __shared__ unsigned short As[128][64];   // 16 KB, chunk-swizzled
    __shared__ unsigned short Bs[128][64];

    const int t = threadIdx.x, lane = t & 63, wid = t >> 6;
    const int fr = lane & 15, g = lane >> 4;
    const int m0 = blockIdx.y * 128;
    const int nglob = blockIdx.x * 128;
    const int mat = nglob >> 10;
    const int n0 = nglob & 1023;
    const float scale = (mat == 0) ? scale0 : 1.f;
    const int wm = (wid >> 1) * 64, wn = (wid & 1) * 64;

    f32x4 acc[4][4] = {};

    int srow[4], skof[4], sdst[4];
#pragma unroll
    for (int c = 0; c < 4; ++c) {
        const int chunk = c * 256 + t;
        srow[c] = chunk >> 3;
        skof[c] = ((chunk & 7) ^ (srow[c] & 7)) * 8;
        sdst[c] = chunk * 8;
    }

    const unsigned short* Abase = A  + (size_t)m0 * D_;
    const unsigned short* Bbase = Bt + (size_t)nglob * D_;

    for (int k0 = 0; k0 < D_; k0 += 64) {
        __syncthreads();
#pragma unroll
        for (int c = 0; c < 4; ++c) {
            __builtin_amdgcn_global_load_lds(
                (const __attribute__((address_space(1))) void*)(Abase + (size_t)srow[c] * D_ + k0 + skof[c]),
                (__attribute__((address_space(3))) void*)(&As[0][0] + sdst[c]), 16, 0, 0);
            __builtin_amdgcn_global_load_lds(
                (const __attribute__((address_space(1))) void*)(Bbase + (size_t)srow[c] * D_ + k0 + skof[c]),
                (__attribute__((address_space(3))) void*)(&Bs[0][0] + sdst[c]), 16, 0, 0);
        }
        __syncthreads();

#pragma unroll
        for (int kb = 0; kb < 2; ++kb) {
            bf16x8 av[4], bv[4];
#pragma unroll
            for (int i = 0; i < 4; ++i) {
                const int ra = wm + i * 16 + fr;
                av[i] = *(const bf16x8*)&As[ra][(((kb << 2) + g) ^ (ra & 7)) * 8];
                const int rb = wn + i * 16 + fr;
                bv[i] = *(const bf16x8*)&Bs[rb][(((kb << 2) + g) ^ (rb & 7)) * 8];
            }
#pragma unroll
            for (int i = 0; i < 4; ++i)
#pragma unroll
                for (int j = 0; j < 4; ++j)
                    acc[i][j] = __builtin_amdgcn_mfma_f32_16x16x32_bf16(av[i], bv[j], acc[i][j], 0, 0, 0);
        }
    }

    const int orow = g * 4;
    if (Cb) {
        unsigned short* Cp = Cb + (size_t)mat * NLD;
#pragma unroll
        for (int i = 0; i < 4; ++i)
#pragma unroll
            for (int j = 0; j < 4; ++j) {
                unsigned short* cp = Cp + (size_t)(m0 + wm + i * 16 + orow) * D_ + n0 + wn + j * 16 + fr;
#pragma unroll
                for (int rg = 0; rg < 4; ++rg)
                    cp[(size_t)rg * D_] = f2bf(acc[i][j][rg] * scale);
            }
    } else {
#pragma unroll
        for (int i = 0; i < 4; ++i)
#pragma unroll
            for (int j = 0; j < 4; ++j) {
                float* cp = Cf + (size_t)(m0 + wm + i * 16 + orow) * D_ + n0 + wn + j * 16 + fr;
#pragma unroll
                for (int rg = 0; rg < 4; ++rg)
                    cp[(size_t)rg * D_] = acc[i][j][rg] * scale;
            }
    }
}

// ------------------------------------------------------------------
// MFMA flash attention, bf16 in/out. q pre-scaled by log2e -> exp2f.
// ------------------------------------------------------------------
__device__ __forceinline__ void stage_k(const unsigned short* src, unsigned short* dst, int t)
{
#pragma unroll
    for (int it = 0; it < 2; ++it) {
        const int c = it * 256 + t;
        const int j = c >> 3;
        const int sc = (c & 7) ^ (j & 7);
        __builtin_amdgcn_global_load_lds(
            (const __attribute__((address_space(1))) void*)(src + (size_t)j * D_ + sc * 8),
            (__attribute__((address_space(3))) void*)(dst + c * 8), 16, 0, 0);
    }
}

__device__ __forceinline__ void write_vt(unsigned short (*Vtl)[64], int jp, int d0, bf16x8 a, bf16x8 b)
{
    const int jlo = (2 * jp) & 7;   // even
    const int jc  = jp >> 2;        // logical j-chunk
#pragma unroll
    for (int e = 0; e < 8; ++e) {
        const int d = d0 + e;
        const unsigned int val = (unsigned int)(unsigned short)a[e]
                               | ((unsigned int)(unsigned short)b[e] << 16);
        *(unsigned int*)&Vtl[d][((jc ^ (d & 7)) << 3) + jlo] = val;
    }
}

__global__ __launch_bounds__(256)
void attn_mfma(const unsigned short* __restrict__ Qb, const unsigned short* __restrict__ Kb,
               const unsigned short* __restrict__ Vb,
               const unsigned short* __restrict__ relkb,   // [144][64] bf16
               const unsigned short* __restrict__ relvT,   // [64][136] bf16
               const float* __restrict__ relv,             // [129][64] f32
               unsigned short* __restrict__ Ob)
{
    __shared__ unsigned short Klds[2][64][64];
    __shared__ unsigned short Vt[2][64][64];
    __shared__ unsigned short Plds[64][72];
    __shared__ unsigned short QRs[64][128];
    __shared__ unsigned short Wsum[64][136];

    const int t    = threadIdx.x;
    const int lane = t & 63;
    const int w    = t >> 6;
    const int fr   = lane & 15;
    const int g    = lane >> 4;
    const int rg0  = g * 4;

    const int bx  = blockIdx.x;
    const int xcd = bx & 7, slot = bx >> 3;
    const int bh  = (xcd << 2) | (slot >> 4);
    const int rb  = slot & 15;
    const int b   = bh >> 4, h = bh & 15;
    const int i0  = rb * 64;
    const size_t head = (size_t)b * L_ * D_ + (size_t)h * DH_;

    const unsigned short* Kh = Kb + head;
    const unsigned short* Vh = Vb + head;

    // issue tile-0 K DMA immediately
    stage_k(Kh, &Klds[0][0][0], t);

    // tile-0 V into regs
    const int jp = t & 31, d0v = ((t >> 5) & 7) * 8;
    bf16x8 va  = *(const bf16x8*)(Vh + (size_t)(2 * jp) * D_ + d0v);
    bf16x8 vb2 = *(const bf16x8*)(Vh + (size_t)(2 * jp + 1) * D_ + d0v);

    // zero Wsum
    {
        unsigned int* wp = (unsigned int*)&Wsum[0][0];
        for (int i = t; i < 64 * 136 / 2; i += 256) wp[i] = 0u;
    }

    // Q fragments
    bf16x8 qf[2];
    {
        const unsigned short* qp = Qb + head + (size_t)(i0 + w * 16 + fr) * D_;
        qf[0] = *(const bf16x8*)(qp + g * 8);
        qf[1] = *(const bf16x8*)(qp + 32 + g * 8);
    }

    // QR[i][r] = q.relk[r] (log2 units); 9 col-frags, store interior cols only
    float qr0[4], qr128[4];
#pragma unroll
    for (int rc = 0; rc < 9; ++rc) {
        f32x4 acc = {};
#pragma unroll
        for (int kb = 0; kb < 2; ++kb) {
            bf16x8 rv = *(const bf16x8*)&relkb[(size_t)(rc * 16 + fr) * 64 + kb * 32 + g * 8];
            acc = __builtin_amdgcn_mfma_f32_16x16x32_bf16(qf[kb], rv, acc, 0, 0, 0);
        }
        if (rc < 8) {
#pragma unroll
            for (int reg = 0; reg < 4; ++reg)
                QRs[w * 16 + rg0 + reg][rc * 16 + fr] = f2bf(acc[reg]);
        }
        if (rc == 0) {
#pragma unroll
            for (int reg = 0; reg < 4; ++reg) qr0[reg] = __shfl(acc[reg], g * 16, 64);
        }
        if (rc == 8) {
#pragma unroll
            for (int reg = 0; reg < 4; ++reg) qr128[reg] = __shfl(acc[reg], g * 16, 64);
        }
    }

    write_vt(Vt[0], jp, d0v, va, vb2);
    asm volatile("s_waitcnt vmcnt(0)" ::: "memory");
    __syncthreads();

    f32x4 oacc[4] = {};
    float lpart[4] = {}, pe0p[4] = {}, pe128p[4] = {};

    int bb = 0;
    for (int jt = 0; jt < 16; ++jt) {
        const bool pre = (jt < 15);
        if (pre) {
            stage_k(Kh + (size_t)(jt + 1) * 64 * D_, &Klds[bb ^ 1][0][0], t);
            const unsigned short* vp = Vh + (size_t)((jt + 1) * 64 + 2 * jp) * D_ + d0v;
            va  = *(const bf16x8*)vp;
            vb2 = *(const bf16x8*)(vp + D_);
        }

        // ---- S = q @ K^T ----
        f32x4 s[4];
#pragma unroll
        for (int fc = 0; fc < 4; ++fc) {
            f32x4 a = {};
            const int j = fc * 16 + fr;
#pragma unroll
            for (int kb = 0; kb < 2; ++kb) {
                bf16x8 kv = *(const bf16x8*)&Klds[bb][j][(((kb << 2) + g) ^ (j & 7)) * 8];
                a = __builtin_amdgcn_mfma_f32_16x16x32_bf16(qf[kb], kv, a, 0, 0, 0);
            }
            s[fc] = a;
        }

        const int dt = (jt - rb) * 64;
        if (dt <= -128 || dt >= 128) {
            const bool lo = dt < 0;
#pragma unroll
            for (int reg = 0; reg < 4; ++reg) {
                const float qrc = lo ? qr0[reg] : qr128[reg];
                float rsum = 0.f;
#pragma unroll
                for (int fc = 0; fc < 4; ++fc) {
                    float pe = exp2f(s[fc][reg] + qrc);
                    rsum += pe;
                    Plds[w * 16 + rg0 + reg][fc * 16 + fr] = f2bf(pe);
                }
                lpart[reg] += rsum;
                if (lo) pe0p[reg] += rsum; else pe128p[reg] += rsum;
            }
        } else {
#pragma unroll
            for (int fc = 0; fc < 4; ++fc) {
#pragma unroll
                for (int reg = 0; reg < 4; ++reg) {
                    const int li  = w * 16 + rg0 + reg;
                    const int rel = dt + fc * 16 + fr - li;
                    float bias;
                    if (rel <= -M_)     bias = qr0[reg];
                    else if (rel >= M_) bias = qr128[reg];
                    else                bias = bf2f(QRs[li][rel + M_]);
                    float pe = exp2f(s[fc][reg] + bias);
                    lpart[reg] += pe;
                    Plds[li][fc * 16 + fr] = f2bf(pe);
                    if (rel <= -M_)      pe0p[reg]   += pe;
                    else if (rel >= M_)  pe128p[reg] += pe;
                    else                 Wsum[li][rel + M_] = f2bf(pe);
                }
            }
        }

        asm volatile("s_waitcnt lgkmcnt(0)" ::: "memory");

        // ---- PV ----
        bf16x8 pa0 = *(const bf16x8*)&Plds[w * 16 + fr][g * 8];
        bf16x8 pa1 = *(const bf16x8*)&Plds[w * 16 + fr][32 + g * 8];
#pragma unroll
        for (int fd = 0; fd < 4; ++fd) {
            const int d = fd * 16 + fr;
            bf16x8 vv0 = *(const bf16x8*)&Vt[bb][d][((g)     ^ (d & 7)) * 8];
            bf16x8 vv1 = *(const bf16x8*)&Vt[bb][d][((4 + g) ^ (d & 7)) * 8];
            oacc[fd] = __builtin_amdgcn_mfma_f32_16x16x32_bf16(pa0, vv0, oacc[fd], 0, 0, 0);
            oacc[fd] = __builtin_amdgcn_mfma_f32_16x16x32_bf16(pa1, vv1, oacc[fd], 0, 0, 0);
        }

        if (pre) write_vt(Vt[bb ^ 1], jp, d0v, va, vb2);
        asm volatile("s_waitcnt vmcnt(0)" ::: "memory");
        __syncthreads();
        bb ^= 1;
    }

    // ---- reduce row partials across 16 fr-lanes ----
#pragma unroll
    for (int m = 1; m <= 8; m <<= 1) {
#pragma unroll
        for (int reg = 0; reg < 4; ++reg) {
            lpart[reg]  += __shfl_xor(lpart[reg],  m, 64);
            pe0p[reg]   += __shfl_xor(pe0p[reg],   m, 64);
            pe128p[reg] += __shfl_xor(pe128p[reg], m, 64);
        }
    }
    if (fr == 0) {
#pragma unroll
        for (int reg = 0; reg < 4; ++reg) {
            Wsum[w * 16 + rg0 + reg][0]   = f2bf(pe0p[reg]);
            Wsum[w * 16 + rg0 + reg][128] = f2bf(pe128p[reg]);
        }
    }
    asm volatile("s_waitcnt lgkmcnt(0)" ::: "memory");
    __syncthreads();

    // ---- o += wsum @ relv (r 0..127 MFMA; r=128 scalar) ----
#pragma unroll
    for (int kc = 0; kc < 4; ++kc) {
        bf16x8 wa = *(const bf16x8*)&Wsum[w * 16 + fr][kc * 32 + g * 8];
#pragma unroll
        for (int fd = 0; fd < 4; ++fd) {
            bf16x8 rv = *(const bf16x8*)&relvT[(size_t)(fd * 16 + fr) * 136 + kc * 32 + g * 8];
            oacc[fd] = __builtin_amdgcn_mfma_f32_16x16x32_bf16(wa, rv, oacc[fd], 0, 0, 0);
        }
    }

    float inv[4];
#pragma unroll
    for (int reg = 0; reg < 4; ++reg) inv[reg] = 1.f / lpart[reg];

#pragma unroll
    for (int fd = 0; fd < 4; ++fd) {
        const float r128 = relv[128 * 64 + fd * 16 + fr];
        unsigned short* op = Ob + head + (size_t)(i0 + w * 16 + rg0) * D_ + fd * 16 + fr;
#pragma unroll
        for (int reg = 0; reg < 4; ++reg)
            op[(size_t)reg * D_] = f2bf((oacc[fd][reg] + pe128p[reg] * r128) * inv[reg]);
    }
}

// ------------------------------------------------------------------
extern "C" void kernel_launch(void* const* d_in, const int* in_sizes, int n_in,
                              void* d_out, int out_size, void* d_ws, size_t ws_size,
                              hipStream_t stream)
{
    const float* x    = (const float*)d_in[0];
    const float* Wq   = (const float*)d_in[1];
    const float* Wk   = (const float*)d_in[2];
    const float* Wv   = (const float*)d_in[3];
    const float* Wo   = (const float*)d_in[4];
    const float* relk = (const float*)d_in[5];
    const float* relv = (const float*)d_in[6];
    float* out = (float*)d_out;

    unsigned short* xb    = (unsigned short*)d_ws;
    unsigned short* Wt    = xb + NLD;            // 4 matrices [n][k]
    unsigned short* relkb = Wt + 4 * DD;         // 144*64
    unsigned short* relvT = relkb + 144 * 64;    // 64*136
    unsigned short* QKVb  = relvT + 64 * 136;    // 3*NLD (Q,K,V contiguous)
    unsigned short* Ob    = QKVb + 3 * NLD;      // NLD

    prep<<<dim3(6180), 256, 0, stream>>>(x, Wq, Wk, Wv, Wo, relk, relv, xb, Wt, relkb, relvT);

    gemm128<<<dim3(24, 16), 256, 0, stream>>>(xb, Wt, QKVb, nullptr, QSCALE);   // Q,K,V fused

    attn_mfma<<<dim3(512), 256, 0, stream>>>(QKVb, QKVb + NLD, QKVb + 2 * NLD,
                                             relkb, relvT, relv, Ob);

    gemm128<<<dim3(8, 16), 256, 0, stream>>>(Ob, Wt + 3 * DD, nullptr, out, 1.f);
}

// Round 6
// 91.632 us; speedup vs baseline: 7.5298x; 1.0335x over previous
//
#include <hip/hip_runtime.h>
#include <hip/hip_bf16.h>
#include <math.h>

#define B_ 2
#define L_ 1024
#define D_ 1024
#define H_ 16
#define DH_ 64
#define M_ 64
#define R_ 129
#define NLD ((size_t)B_ * L_ * D_)          // 2,097,152
#define DD  ((size_t)D_ * D_)
#define QSCALE 0.18033688011112042f         // DH^-0.5 * log2(e)

using bf16x8 = __attribute__((ext_vector_type(8))) short;
using f32x4  = __attribute__((ext_vector_type(4))) float;

__device__ __forceinline__ unsigned short f2bf(float f) {
    unsigned int x = __builtin_bit_cast(unsigned int, f);
    unsigned int r = x + 0x7fffu + ((x >> 16) & 1u);   // RNE
    return (unsigned short)(r >> 16);
}
__device__ __forceinline__ float bf2f(unsigned short u) {
    unsigned int x = ((unsigned int)u) << 16;
    return __builtin_bit_cast(float, x);
}
__device__ __forceinline__ unsigned int pk2bf(float lo, float hi) {
    return (unsigned int)f2bf(lo) | ((unsigned int)f2bf(hi) << 16);
}

// ------------------------------------------------------------------
// prep: [0,2048) x->bf16 | [2048,6144) W transposes | [6144,6180) rel tables
// ------------------------------------------------------------------
__global__ __launch_bounds__(256)
void prep(const float* __restrict__ x,
          const float* __restrict__ W0, const float* __restrict__ W1,
          const float* __restrict__ W2, const float* __restrict__ W3,
          const float* __restrict__ relk, const float* __restrict__ relv,
          unsigned short* __restrict__ xb, unsigned short* __restrict__ Wt,
          unsigned short* __restrict__ relkb, unsigned short* __restrict__ relvT)
{
    __shared__ float tile[32][33];
    const int bid = blockIdx.x, t = threadIdx.x;
    if (bid < 2048) {
        const int i = bid * 256 + t;
        float4 v = ((const float4*)x)[i];
        short4 o = { (short)f2bf(v.x), (short)f2bf(v.y), (short)f2bf(v.z), (short)f2bf(v.w) };
        ((short4*)xb)[i] = o;
    } else if (bid < 6144) {
        const int wb = bid - 2048;
        const int z = wb >> 10, rem = wb & 1023;
        const float* W = z == 0 ? W0 : z == 1 ? W1 : z == 2 ? W2 : W3;
        unsigned short* T = Wt + (size_t)z * DD;
        const int k0 = (rem >> 5) * 32, n0 = (rem & 31) * 32;
        const int r = t >> 3, c = (t & 7) * 4;
        float4 v = *(const float4*)&W[(size_t)(k0 + r) * D_ + n0 + c];
        tile[r][c] = v.x; tile[r][c + 1] = v.y; tile[r][c + 2] = v.z; tile[r][c + 3] = v.w;
        __syncthreads();
        short4 o = { (short)f2bf(tile[c][r]),     (short)f2bf(tile[c + 1][r]),
                     (short)f2bf(tile[c + 2][r]), (short)f2bf(tile[c + 3][r]) };
        *(short4*)&T[(size_t)(n0 + r) * D_ + k0 + c] = o;
    } else {
        const int idx = (bid - 6144) * 256 + t;
        if (idx < 144 * 64) {
            const int r = idx >> 6, d = idx & 63;
            relkb[idx] = (r < R_) ? f2bf(relk[r * 64 + d]) : (unsigned short)0;
        }
        if (idx < 64 * 136) {
            const int d = idx / 136, r = idx - d * 136;
            relvT[idx] = (r < R_) ? f2bf(relv[r * 64 + d]) : (unsigned short)0;
        }
    }
}

// ------------------------------------------------------------------
// 128x128-tile bf16 MFMA GEMM (m97 structure) — unchanged from R4
// ------------------------------------------------------------------
__global__ __launch_bounds__(256)
void gemm128(const unsigned short* __restrict__ A, const unsigned short* __restrict__ Bt,
             unsigned short* __restrict__ Cb, float* __restrict__ Cf, float scale0)
{
    __shared__ unsigned short As[128][64];
    __shared__ unsigned short Bs[128][64];

    const int t = threadIdx.x, lane = t & 63, wid = t >> 6;
    const int fr = lane & 15, g = lane >> 4;
    const int m0 = blockIdx.y * 128;
    const int nglob = blockIdx.x * 128;
    const int mat = nglob >> 10;
    const int n0 = nglob & 1023;
    const float scale = (mat == 0) ? scale0 : 1.f;
    const int wm = (wid >> 1) * 64, wn = (wid & 1) * 64;

    f32x4 acc[4][4] = {};

    int srow[4], skof[4], sdst[4];
#pragma unroll
    for (int c = 0; c < 4; ++c) {
        const int chunk = c * 256 + t;
        srow[c] = chunk >> 3;
        skof[c] = ((chunk & 7) ^ (srow[c] & 7)) * 8;
        sdst[c] = chunk * 8;
    }

    const unsigned short* Abase = A  + (size_t)m0 * D_;
    const unsigned short* Bbase = Bt + (size_t)nglob * D_;

    for (int k0 = 0; k0 < D_; k0 += 64) {
        __syncthreads();
#pragma unroll
        for (int c = 0; c < 4; ++c) {
            __builtin_amdgcn_global_load_lds(
                (const __attribute__((address_space(1))) void*)(Abase + (size_t)srow[c] * D_ + k0 + skof[c]),
                (__attribute__((address_space(3))) void*)(&As[0][0] + sdst[c]), 16, 0, 0);
            __builtin_amdgcn_global_load_lds(
                (const __attribute__((address_space(1))) void*)(Bbase + (size_t)srow[c] * D_ + k0 + skof[c]),
                (__attribute__((address_space(3))) void*)(&Bs[0][0] + sdst[c]), 16, 0, 0);
        }
        __syncthreads();

#pragma unroll
        for (int kb = 0; kb < 2; ++kb) {
            bf16x8 av[4], bv[4];
#pragma unroll
            for (int i = 0; i < 4; ++i) {
                const int ra = wm + i * 16 + fr;
                av[i] = *(const bf16x8*)&As[ra][(((kb << 2) + g) ^ (ra & 7)) * 8];
                const int rb = wn + i * 16 + fr;
                bv[i] = *(const bf16x8*)&Bs[rb][(((kb << 2) + g) ^ (rb & 7)) * 8];
            }
#pragma unroll
            for (int i = 0; i < 4; ++i)
#pragma unroll
                for (int j = 0; j < 4; ++j)
                    acc[i][j] = __builtin_amdgcn_mfma_f32_16x16x32_bf16(av[i], bv[j], acc[i][j], 0, 0, 0);
        }
    }

    const int orow = g * 4;
    if (Cb) {
        unsigned short* Cp = Cb + (size_t)mat * NLD;
#pragma unroll
        for (int i = 0; i < 4; ++i)
#pragma unroll
            for (int j = 0; j < 4; ++j) {
                unsigned short* cp = Cp + (size_t)(m0 + wm + i * 16 + orow) * D_ + n0 + wn + j * 16 + fr;
#pragma unroll
                for (int rg = 0; rg < 4; ++rg)
                    cp[(size_t)rg * D_] = f2bf(acc[i][j][rg] * scale);
            }
    } else {
#pragma unroll
        for (int i = 0; i < 4; ++i)
#pragma unroll
            for (int j = 0; j < 4; ++j) {
                float* cp = Cf + (size_t)(m0 + wm + i * 16 + orow) * D_ + n0 + wn + j * 16 + fr;
#pragma unroll
                for (int rg = 0; rg < 4; ++rg)
                    cp[(size_t)rg * D_] = acc[i][j][rg] * scale;
            }
    }
}

// ------------------------------------------------------------------
// MFMA flash attention, swapped QK^T (S^T = K·Q^T): lane fr owns q-row,
// 16 consecutive-j S values -> packed softmax, intra-wave P/QR/Wsum.
// ------------------------------------------------------------------
__device__ __forceinline__ void stage_k(const unsigned short* src, unsigned short* dst, int t)
{
#pragma unroll
    for (int it = 0; it < 2; ++it) {
        const int c = it * 256 + t;
        const int j = c >> 3;
        const int sc = (c & 7) ^ (j & 7);
        __builtin_amdgcn_global_load_lds(
            (const __attribute__((address_space(1))) void*)(src + (size_t)j * D_ + sc * 8),
            (__attribute__((address_space(3))) void*)(dst + c * 8), 16, 0, 0);
    }
}

__device__ __forceinline__ void write_vt(unsigned short (*Vtl)[64], int jp, int d0, bf16x8 a, bf16x8 b)
{
    const int jlo = (2 * jp) & 7;
    const int jc  = jp >> 2;
#pragma unroll
    for (int e = 0; e < 8; ++e) {
        const int d = d0 + e;
        const unsigned int val = (unsigned int)(unsigned short)a[e]
                               | ((unsigned int)(unsigned short)b[e] << 16);
        *(unsigned int*)&Vtl[d][((jc ^ (d & 7)) << 3) + jlo] = val;
    }
}

__global__ __launch_bounds__(256)
void attn_mfma(const unsigned short* __restrict__ Qb, const unsigned short* __restrict__ Kb,
               const unsigned short* __restrict__ Vb,
               const unsigned short* __restrict__ relkb,   // [144][64] bf16
               const unsigned short* __restrict__ relvT,   // [64][136] bf16
               const float* __restrict__ relv,             // [129][64] f32
               unsigned short* __restrict__ Ob)
{
    __shared__ unsigned short Klds[2][64][64];
    __shared__ unsigned short Vt[2][64][64];
    __shared__ unsigned short Plds[64][72];
    __shared__ unsigned short QRs[64][136];
    __shared__ unsigned short Wsum[64][136];

    const int t    = threadIdx.x;
    const int lane = t & 63;
    const int w    = t >> 6;
    const int fr   = lane & 15;
    const int g    = lane >> 4;

    const int bx  = blockIdx.x;
    const int xcd = bx & 7, slot = bx >> 3;
    const int bh  = (xcd << 2) | (slot >> 4);
    const int rb  = slot & 15;
    const int b   = bh >> 4, h = bh & 15;
    const int i0  = rb * 64;
    const size_t head = (size_t)b * L_ * D_ + (size_t)h * DH_;

    const int iloc = w * 16 + fr;      // this lane's q-row within the block

    const unsigned short* Kh = Kb + head;
    const unsigned short* Vh = Vb + head;

    stage_k(Kh, &Klds[0][0][0], t);

    const int jp = t & 31, d0v = ((t >> 5) & 7) * 8;
    bf16x8 va  = *(const bf16x8*)(Vh + (size_t)(2 * jp) * D_ + d0v);
    bf16x8 vb2 = *(const bf16x8*)(Vh + (size_t)(2 * jp + 1) * D_ + d0v);

    {
        unsigned int* wp = (unsigned int*)&Wsum[0][0];
        for (int i = t; i < 64 * 136 / 2; i += 256) wp[i] = 0u;
    }

    // Q fragments (lane fr = q-row iloc)
    bf16x8 qf[2];
    {
        const unsigned short* qp = Qb + head + (size_t)(i0 + iloc) * D_;
        qf[0] = *(const bf16x8*)(qp + g * 8);
        qf[1] = *(const bf16x8*)(qp + 32 + g * 8);
    }

    // QR^T = relk @ q^T : lane fr = q-row, rows g*4+reg = rel idx -> packed stores
#pragma unroll
    for (int rc = 0; rc < 9; ++rc) {
        f32x4 acc = {};
#pragma unroll
        for (int kb = 0; kb < 2; ++kb) {
            bf16x8 rv = *(const bf16x8*)&relkb[(size_t)(rc * 16 + fr) * 64 + kb * 32 + g * 8];
            acc = __builtin_amdgcn_mfma_f32_16x16x32_bf16(rv, qf[kb], acc, 0, 0, 0);
        }
        if (rc < 8) {
            uint2 pk = { pk2bf(acc[0], acc[1]), pk2bf(acc[2], acc[3]) };
            *(uint2*)&QRs[iloc][rc * 16 + g * 4] = pk;
        } else if (g == 0) {
            QRs[iloc][128] = f2bf(acc[0]);   // r = 128
        }
    }

    write_vt(Vt[0], jp, d0v, va, vb2);
    asm volatile("s_waitcnt vmcnt(0)" ::: "memory");
    __syncthreads();

    const float qr0   = bf2f(QRs[iloc][0]);
    const float qr128 = bf2f(QRs[iloc][128]);

    f32x4 oacc[4] = {};
    float lpart = 0.f, pe0p = 0.f, pe128p = 0.f;

    int bb = 0;
    for (int jt = 0; jt < 16; ++jt) {
        const bool pre = (jt < 15);
        if (pre) {
            stage_k(Kh + (size_t)(jt + 1) * 64 * D_, &Klds[bb ^ 1][0][0], t);
            const unsigned short* vp = Vh + (size_t)((jt + 1) * 64 + 2 * jp) * D_ + d0v;
            va  = *(const bf16x8*)vp;
            vb2 = *(const bf16x8*)(vp + D_);
        }

        // ---- S^T = K @ Q^T : s[fc][reg] = S[i=iloc][j = fc*16 + g*4 + reg] ----
        f32x4 s[4];
        __builtin_amdgcn_s_setprio(1);
#pragma unroll
        for (int fc = 0; fc < 4; ++fc) {
            f32x4 a = {};
            const int j = fc * 16 + fr;
#pragma unroll
            for (int kb = 0; kb < 2; ++kb) {
                bf16x8 kv = *(const bf16x8*)&Klds[bb][j][(((kb << 2) + g) ^ (j & 7)) * 8];
                a = __builtin_amdgcn_mfma_f32_16x16x32_bf16(kv, qf[kb], a, 0, 0, 0);
            }
            s[fc] = a;
        }
        __builtin_amdgcn_s_setprio(0);

        const int dt   = (jt - rb) * 64;
        const int relb = dt - iloc + g * 4;    // rel for (fc=0, reg=0)

        if (dt <= -128 || dt >= 128) {
            // FAR: constant bias per row
            const float qrc = (dt < 0) ? qr0 : qr128;
            float tsum = 0.f;
#pragma unroll
            for (int fc = 0; fc < 4; ++fc) {
                float p0 = exp2f(s[fc][0] + qrc);
                float p1 = exp2f(s[fc][1] + qrc);
                float p2 = exp2f(s[fc][2] + qrc);
                float p3 = exp2f(s[fc][3] + qrc);
                uint2 pk = { pk2bf(p0, p1), pk2bf(p2, p3) };
                *(uint2*)&Plds[iloc][fc * 16 + g * 4] = pk;
                tsum += (p0 + p1) + (p2 + p3);
            }
            lpart += tsum;
            if (dt < 0) pe0p += tsum; else pe128p += tsum;
        } else if (dt == 0) {
            // MID: fully interior
#pragma unroll
            for (int fc = 0; fc < 4; ++fc) {
                const int c0 = relb + fc * 16 + M_;
                float pe[4];
#pragma unroll
                for (int reg = 0; reg < 4; ++reg) {
                    pe[reg] = exp2f(s[fc][reg] + bf2f(QRs[iloc][c0 + reg]));
                    lpart += pe[reg];
                }
                uint2 pk = { pk2bf(pe[0], pe[1]), pk2bf(pe[2], pe[3]) };
                *(uint2*)&Plds[iloc][fc * 16 + g * 4] = pk;
                Wsum[iloc][c0 + 0] = (unsigned short)(pk.x & 0xffffu);
                Wsum[iloc][c0 + 1] = (unsigned short)(pk.x >> 16);
                Wsum[iloc][c0 + 2] = (unsigned short)(pk.y & 0xffffu);
                Wsum[iloc][c0 + 3] = (unsigned short)(pk.y >> 16);
            }
        } else {
            // EDGE (dt = ±64): clamped-column bias, routed accumulation
#pragma unroll
            for (int fc = 0; fc < 4; ++fc) {
                float pe[4];
#pragma unroll
                for (int reg = 0; reg < 4; ++reg) {
                    const int colr = relb + fc * 16 + reg + M_;
                    const int col  = colr < 0 ? 0 : (colr > 128 ? 128 : colr);
                    pe[reg] = exp2f(s[fc][reg] + bf2f(QRs[iloc][col]));
                    lpart += pe[reg];
                    if (col == 0)        pe0p   += pe[reg];
                    else if (col == 128) pe128p += pe[reg];
                    else                 Wsum[iloc][col] = f2bf(pe[reg]);
                }
                uint2 pk = { pk2bf(pe[0], pe[1]), pk2bf(pe[2], pe[3]) };
                *(uint2*)&Plds[iloc][fc * 16 + g * 4] = pk;
            }
        }

        asm volatile("s_waitcnt lgkmcnt(0)" ::: "memory");
        __builtin_amdgcn_sched_barrier(0);

        // ---- PV: A = P rows (lane fr = row), B = V^T ----
        bf16x8 pa0 = *(const bf16x8*)&Plds[iloc][g * 8];
        bf16x8 pa1 = *(const bf16x8*)&Plds[iloc][32 + g * 8];
        __builtin_amdgcn_s_setprio(1);
#pragma unroll
        for (int fd = 0; fd < 4; ++fd) {
            const int d = fd * 16 + fr;
            bf16x8 vv0 = *(const bf16x8*)&Vt[bb][d][((g)     ^ (d & 7)) * 8];
            bf16x8 vv1 = *(const bf16x8*)&Vt[bb][d][((4 + g) ^ (d & 7)) * 8];
            oacc[fd] = __builtin_amdgcn_mfma_f32_16x16x32_bf16(pa0, vv0, oacc[fd], 0, 0, 0);
            oacc[fd] = __builtin_amdgcn_mfma_f32_16x16x32_bf16(pa1, vv1, oacc[fd], 0, 0, 0);
        }
        __builtin_amdgcn_s_setprio(0);

        if (pre) write_vt(Vt[bb ^ 1], jp, d0v, va, vb2);
        asm volatile("s_waitcnt vmcnt(0)" ::: "memory");
        __syncthreads();
        bb ^= 1;
    }

    // ---- finalize row partials (per-lane scalars; reduce across g-groups) ----
    lpart  += __shfl_xor(lpart, 16);  lpart  += __shfl_xor(lpart, 32);
    pe0p   += __shfl_xor(pe0p, 16);   pe0p   += __shfl_xor(pe0p, 32);
    pe128p += __shfl_xor(pe128p, 16); pe128p += __shfl_xor(pe128p, 32);
    if (g == 0) {
        Wsum[iloc][0]   = f2bf(pe0p);
        Wsum[iloc][128] = f2bf(pe128p);
    }
    asm volatile("s_waitcnt lgkmcnt(0)" ::: "memory");
    __builtin_amdgcn_sched_barrier(0);

    // ---- o += wsum @ relv (r 0..127 MFMA; r=128 scalar) ----
#pragma unroll
    for (int kc = 0; kc < 4; ++kc) {
        bf16x8 wa = *(const bf16x8*)&Wsum[iloc][kc * 32 + g * 8];
#pragma unroll
        for (int fd = 0; fd < 4; ++fd) {
            bf16x8 rv = *(const bf16x8*)&relvT[(size_t)(fd * 16 + fr) * 136 + kc * 32 + g * 8];
            oacc[fd] = __builtin_amdgcn_mfma_f32_16x16x32_bf16(wa, rv, oacc[fd], 0, 0, 0);
        }
    }

    // redistribute lpart/pe128p from row-lane (fr) to C-layout rows (g*4+reg)
    float invd[4], pr128[4];
#pragma unroll
    for (int reg = 0; reg < 4; ++reg) {
        const int src = (lane & 48) | (g * 4 + reg);
        invd[reg]  = 1.f / __shfl(lpart, src, 64);
        pr128[reg] = __shfl(pe128p, src, 64);
    }

#pragma unroll
    for (int fd = 0; fd < 4; ++fd) {
        const float r128 = relv[128 * 64 + fd * 16 + fr];
        unsigned short* op = Ob + head + (size_t)(i0 + w * 16 + g * 4) * D_ + fd * 16 + fr;
#pragma unroll
        for (int reg = 0; reg < 4; ++reg)
            op[(size_t)reg * D_] = f2bf((oacc[fd][reg] + pr128[reg] * r128) * invd[reg]);
    }
}

// ------------------------------------------------------------------
extern "C" void kernel_launch(void* const* d_in, const int* in_sizes, int n_in,
                              void* d_out, int out_size, void* d_ws, size_t ws_size,
                              hipStream_t stream)
{
    const float* x    = (const float*)d_in[0];
    const float* Wq   = (const float*)d_in[1];
    const float* Wk   = (const float*)d_in[2];
    const float* Wv   = (const float*)d_in[3];
    const float* Wo   = (const float*)d_in[4];
    const float* relk = (const float*)d_in[5];
    const float* relv = (const float*)d_in[6];
    float* out = (float*)d_out;

    unsigned short* xb    = (unsigned short*)d_ws;
    unsigned short* Wt    = xb + NLD;
    unsigned short* relkb = Wt + 4 * DD;
    unsigned short* relvT = relkb + 144 * 64;
    unsigned short* QKVb  = relvT + 64 * 136;
    unsigned short* Ob    = QKVb + 3 * NLD;

    prep<<<dim3(6180), 256, 0, stream>>>(x, Wq, Wk, Wv, Wo, relk, relv, xb, Wt, relkb, relvT);

    gemm128<<<dim3(24, 16), 256, 0, stream>>>(xb, Wt, QKVb, nullptr, QSCALE);

    attn_mfma<<<dim3(512), 256, 0, stream>>>(QKVb, QKVb + NLD, QKVb + 2 * NLD,
                                             relkb, relvT, relv, Ob);

    gemm128<<<dim3(8, 16), 256, 0, stream>>>(Ob, Wt + 3 * DD, nullptr, out, 1.f);
}

// Round 7
// 82.443 us; speedup vs baseline: 8.3691x; 1.1115x over previous
//
#include <hip/hip_runtime.h>
#include <hip/hip_bf16.h>
#include <math.h>

#define B_ 2
#define L_ 1024
#define D_ 1024
#define H_ 16
#define DH_ 64
#define M_ 64
#define R_ 129
#define NLD ((size_t)B_ * L_ * D_)          // 2,097,152
#define DD  ((size_t)D_ * D_)
#define QSCALE 0.18033688011112042f         // DH^-0.5 * log2(e)

using bf16x8 = __attribute__((ext_vector_type(8))) short;
using f32x4  = __attribute__((ext_vector_type(4))) float;

__device__ __forceinline__ unsigned short f2bf(float f) {
    unsigned int x = __builtin_bit_cast(unsigned int, f);
    unsigned int r = x + 0x7fffu + ((x >> 16) & 1u);   // RNE
    return (unsigned short)(r >> 16);
}
__device__ __forceinline__ float bf2f(unsigned short u) {
    unsigned int x = ((unsigned int)u) << 16;
    return __builtin_bit_cast(float, x);
}
__device__ __forceinline__ unsigned int pk2bf(float lo, float hi) {
    __hip_bfloat162 h = __float22bfloat162_rn(float2{lo, hi});  // v_cvt_pk_bf16_f32 (RNE)
    unsigned int u;
    __builtin_memcpy(&u, &h, 4);
    return u;
}

// ------------------------------------------------------------------
// prep: [0,2048) x->bf16 | [2048,6144) W transposes | [6144,6180) rel tables
// ------------------------------------------------------------------
__global__ __launch_bounds__(256)
void prep(const float* __restrict__ x,
          const float* __restrict__ W0, const float* __restrict__ W1,
          const float* __restrict__ W2, const float* __restrict__ W3,
          const float* __restrict__ relk, const float* __restrict__ relv,
          unsigned short* __restrict__ xb, unsigned short* __restrict__ Wt,
          unsigned short* __restrict__ relkb, unsigned short* __restrict__ relvT)
{
    __shared__ float tile[32][33];
    const int bid = blockIdx.x, t = threadIdx.x;
    if (bid < 2048) {
        const int i = bid * 256 + t;
        float4 v = ((const float4*)x)[i];
        short4 o = { (short)f2bf(v.x), (short)f2bf(v.y), (short)f2bf(v.z), (short)f2bf(v.w) };
        ((short4*)xb)[i] = o;
    } else if (bid < 6144) {
        const int wb = bid - 2048;
        const int z = wb >> 10, rem = wb & 1023;
        const float* W = z == 0 ? W0 : z == 1 ? W1 : z == 2 ? W2 : W3;
        unsigned short* T = Wt + (size_t)z * DD;
        const int k0 = (rem >> 5) * 32, n0 = (rem & 31) * 32;
        const int r = t >> 3, c = (t & 7) * 4;
        float4 v = *(const float4*)&W[(size_t)(k0 + r) * D_ + n0 + c];
        tile[r][c] = v.x; tile[r][c + 1] = v.y; tile[r][c + 2] = v.z; tile[r][c + 3] = v.w;
        __syncthreads();
        short4 o = { (short)f2bf(tile[c][r]),     (short)f2bf(tile[c + 1][r]),
                     (short)f2bf(tile[c + 2][r]), (short)f2bf(tile[c + 3][r]) };
        *(short4*)&T[(size_t)(n0 + r) * D_ + k0 + c] = o;
    } else {
        const int idx = (bid - 6144) * 256 + t;
        if (idx < 144 * 64) {
            const int r = idx >> 6, d = idx & 63;
            relkb[idx] = (r < R_) ? f2bf(relk[r * 64 + d]) : (unsigned short)0;
        }
        if (idx < 64 * 136) {
            const int d = idx / 136, r = idx - d * 136;
            relvT[idx] = (r < R_) ? f2bf(relv[r * 64 + d]) : (unsigned short)0;
        }
    }
}

// ------------------------------------------------------------------
// 64(M)x128(N)-tile bf16 MFMA GEMM, BK=64, 4 waves x 32x64.
// Balanced grids: QKV (24,32)=768 blocks (3/CU); out (8,32)=256 (1/CU).
// ------------------------------------------------------------------
__global__ __launch_bounds__(256)
void gemm64(const unsigned short* __restrict__ A, const unsigned short* __restrict__ Bt,
            unsigned short* __restrict__ Cb, float* __restrict__ Cf, float scale0)
{
    __shared__ unsigned short As[64][64];    // 8 KB, chunk-swizzled
    __shared__ unsigned short Bs[128][64];   // 16 KB

    const int t = threadIdx.x, lane = t & 63, wid = t >> 6;
    const int fr = lane & 15, g = lane >> 4;
    const int m0 = blockIdx.y * 64;
    const int nglob = blockIdx.x * 128;
    const int mat = nglob >> 10;
    const int n0 = nglob & 1023;
    const float scale = (mat == 0) ? scale0 : 1.f;
    const int wm = (wid >> 1) * 32, wn = (wid & 1) * 64;

    f32x4 acc[2][4] = {};

    int arow[2], akof[2], adst[2];
#pragma unroll
    for (int c = 0; c < 2; ++c) {
        const int chunk = c * 256 + t;
        arow[c] = chunk >> 3;
        akof[c] = ((chunk & 7) ^ (arow[c] & 7)) * 8;
        adst[c] = chunk * 8;
    }
    int brow[4], bkof[4], bdst[4];
#pragma unroll
    for (int c = 0; c < 4; ++c) {
        const int chunk = c * 256 + t;
        brow[c] = chunk >> 3;
        bkof[c] = ((chunk & 7) ^ (brow[c] & 7)) * 8;
        bdst[c] = chunk * 8;
    }

    const unsigned short* Abase = A  + (size_t)m0 * D_;
    const unsigned short* Bbase = Bt + (size_t)nglob * D_;

    for (int k0 = 0; k0 < D_; k0 += 64) {
        __syncthreads();
#pragma unroll
        for (int c = 0; c < 2; ++c)
            __builtin_amdgcn_global_load_lds(
                (const __attribute__((address_space(1))) void*)(Abase + (size_t)arow[c] * D_ + k0 + akof[c]),
                (__attribute__((address_space(3))) void*)(&As[0][0] + adst[c]), 16, 0, 0);
#pragma unroll
        for (int c = 0; c < 4; ++c)
            __builtin_amdgcn_global_load_lds(
                (const __attribute__((address_space(1))) void*)(Bbase + (size_t)brow[c] * D_ + k0 + bkof[c]),
                (__attribute__((address_space(3))) void*)(&Bs[0][0] + bdst[c]), 16, 0, 0);
        __syncthreads();

#pragma unroll
        for (int kb = 0; kb < 2; ++kb) {
            bf16x8 av[2], bv[4];
#pragma unroll
            for (int i = 0; i < 2; ++i) {
                const int ra = wm + i * 16 + fr;
                av[i] = *(const bf16x8*)&As[ra][(((kb << 2) + g) ^ (ra & 7)) * 8];
            }
#pragma unroll
            for (int j = 0; j < 4; ++j) {
                const int rb = wn + j * 16 + fr;
                bv[j] = *(const bf16x8*)&Bs[rb][(((kb << 2) + g) ^ (rb & 7)) * 8];
            }
#pragma unroll
            for (int i = 0; i < 2; ++i)
#pragma unroll
                for (int j = 0; j < 4; ++j)
                    acc[i][j] = __builtin_amdgcn_mfma_f32_16x16x32_bf16(av[i], bv[j], acc[i][j], 0, 0, 0);
        }
    }

    const int orow = g * 4;
    if (Cb) {
        unsigned short* Cp = Cb + (size_t)mat * NLD;
#pragma unroll
        for (int i = 0; i < 2; ++i)
#pragma unroll
            for (int j = 0; j < 4; ++j) {
                unsigned short* cp = Cp + (size_t)(m0 + wm + i * 16 + orow) * D_ + n0 + wn + j * 16 + fr;
#pragma unroll
                for (int rg = 0; rg < 4; ++rg)
                    cp[(size_t)rg * D_] = f2bf(acc[i][j][rg] * scale);
            }
    } else {
#pragma unroll
        for (int i = 0; i < 2; ++i)
#pragma unroll
            for (int j = 0; j < 4; ++j) {
                float* cp = Cf + (size_t)(m0 + wm + i * 16 + orow) * D_ + n0 + wn + j * 16 + fr;
#pragma unroll
                for (int rg = 0; rg < 4; ++rg)
                    cp[(size_t)rg * D_] = acc[i][j][rg] * scale;
            }
    }
}

// ------------------------------------------------------------------
// MFMA flash attention, swapped QK^T. pk2bf -> v_cvt_pk; Vt reads hoisted
// above softmax (latency hides under exp2/pack).
// ------------------------------------------------------------------
__device__ __forceinline__ void stage_k(const unsigned short* src, unsigned short* dst, int t)
{
#pragma unroll
    for (int it = 0; it < 2; ++it) {
        const int c = it * 256 + t;
        const int j = c >> 3;
        const int sc = (c & 7) ^ (j & 7);
        __builtin_amdgcn_global_load_lds(
            (const __attribute__((address_space(1))) void*)(src + (size_t)j * D_ + sc * 8),
            (__attribute__((address_space(3))) void*)(dst + c * 8), 16, 0, 0);
    }
}

__device__ __forceinline__ void write_vt(unsigned short (*Vtl)[64], int jp, int d0, bf16x8 a, bf16x8 b)
{
    const int jlo = (2 * jp) & 7;
    const int jc  = jp >> 2;
#pragma unroll
    for (int e = 0; e < 8; ++e) {
        const int d = d0 + e;
        const unsigned int val = (unsigned int)(unsigned short)a[e]
                               | ((unsigned int)(unsigned short)b[e] << 16);
        *(unsigned int*)&Vtl[d][((jc ^ (d & 7)) << 3) + jlo] = val;
    }
}

__global__ __launch_bounds__(256)
void attn_mfma(const unsigned short* __restrict__ Qb, const unsigned short* __restrict__ Kb,
               const unsigned short* __restrict__ Vb,
               const unsigned short* __restrict__ relkb,   // [144][64] bf16
               const unsigned short* __restrict__ relvT,   // [64][136] bf16
               const float* __restrict__ relv,             // [129][64] f32
               unsigned short* __restrict__ Ob)
{
    __shared__ unsigned short Klds[2][64][64];
    __shared__ unsigned short Vt[2][64][64];
    __shared__ unsigned short Plds[64][72];
    __shared__ unsigned short QRs[64][136];
    __shared__ unsigned short Wsum[64][136];

    const int t    = threadIdx.x;
    const int lane = t & 63;
    const int w    = t >> 6;
    const int fr   = lane & 15;
    const int g    = lane >> 4;

    const int bx  = blockIdx.x;
    const int xcd = bx & 7, slot = bx >> 3;
    const int bh  = (xcd << 2) | (slot >> 4);
    const int rb  = slot & 15;
    const int b   = bh >> 4, h = bh & 15;
    const int i0  = rb * 64;
    const size_t head = (size_t)b * L_ * D_ + (size_t)h * DH_;

    const int iloc = w * 16 + fr;

    const unsigned short* Kh = Kb + head;
    const unsigned short* Vh = Vb + head;

    stage_k(Kh, &Klds[0][0][0], t);

    const int jp = t & 31, d0v = ((t >> 5) & 7) * 8;
    bf16x8 va  = *(const bf16x8*)(Vh + (size_t)(2 * jp) * D_ + d0v);
    bf16x8 vb2 = *(const bf16x8*)(Vh + (size_t)(2 * jp + 1) * D_ + d0v);

    {
        unsigned int* wp = (unsigned int*)&Wsum[0][0];
        for (int i = t; i < 64 * 136 / 2; i += 256) wp[i] = 0u;
    }

    bf16x8 qf[2];
    {
        const unsigned short* qp = Qb + head + (size_t)(i0 + iloc) * D_;
        qf[0] = *(const bf16x8*)(qp + g * 8);
        qf[1] = *(const bf16x8*)(qp + 32 + g * 8);
    }

    // QR^T = relk @ q^T
#pragma unroll
    for (int rc = 0; rc < 9; ++rc) {
        f32x4 acc = {};
#pragma unroll
        for (int kb = 0; kb < 2; ++kb) {
            bf16x8 rv = *(const bf16x8*)&relkb[(size_t)(rc * 16 + fr) * 64 + kb * 32 + g * 8];
            acc = __builtin_amdgcn_mfma_f32_16x16x32_bf16(rv, qf[kb], acc, 0, 0, 0);
        }
        if (rc < 8) {
            uint2 pk = { pk2bf(acc[0], acc[1]), pk2bf(acc[2], acc[3]) };
            *(uint2*)&QRs[iloc][rc * 16 + g * 4] = pk;
        } else if (g == 0) {
            QRs[iloc][128] = f2bf(acc[0]);
        }
    }

    write_vt(Vt[0], jp, d0v, va, vb2);
    asm volatile("s_waitcnt vmcnt(0)" ::: "memory");
    __syncthreads();

    const float qr0   = bf2f(QRs[iloc][0]);
    const float qr128 = bf2f(QRs[iloc][128]);

    f32x4 oacc[4] = {};
    float lpart = 0.f, pe0p = 0.f, pe128p = 0.f;

    int bb = 0;
    for (int jt = 0; jt < 16; ++jt) {
        const bool pre = (jt < 15);
        if (pre) {
            stage_k(Kh + (size_t)(jt + 1) * 64 * D_, &Klds[bb ^ 1][0][0], t);
            const unsigned short* vp = Vh + (size_t)((jt + 1) * 64 + 2 * jp) * D_ + d0v;
            va  = *(const bf16x8*)vp;
            vb2 = *(const bf16x8*)(vp + D_);
        }

        // ---- S^T = K @ Q^T ----
        f32x4 s[4];
        __builtin_amdgcn_s_setprio(1);
#pragma unroll
        for (int fc = 0; fc < 4; ++fc) {
            f32x4 a = {};
            const int j = fc * 16 + fr;
#pragma unroll
            for (int kb = 0; kb < 2; ++kb) {
                bf16x8 kv = *(const bf16x8*)&Klds[bb][j][(((kb << 2) + g) ^ (j & 7)) * 8];
                a = __builtin_amdgcn_mfma_f32_16x16x32_bf16(kv, qf[kb], a, 0, 0, 0);
            }
            s[fc] = a;
        }
        __builtin_amdgcn_s_setprio(0);

        // ---- hoist V^T fragment reads: latency hides under softmax ----
        bf16x8 vv0[4], vv1[4];
#pragma unroll
        for (int fd = 0; fd < 4; ++fd) {
            const int d = fd * 16 + fr;
            vv0[fd] = *(const bf16x8*)&Vt[bb][d][((g)     ^ (d & 7)) * 8];
            vv1[fd] = *(const bf16x8*)&Vt[bb][d][((4 + g) ^ (d & 7)) * 8];
        }

        const int dt   = (jt - rb) * 64;
        const int relb = dt - iloc + g * 4;

        if (dt <= -128 || dt >= 128) {
            const float qrc = (dt < 0) ? qr0 : qr128;
            float tsum = 0.f;
#pragma unroll
            for (int fc = 0; fc < 4; ++fc) {
                float p0 = exp2f(s[fc][0] + qrc);
                float p1 = exp2f(s[fc][1] + qrc);
                float p2 = exp2f(s[fc][2] + qrc);
                float p3 = exp2f(s[fc][3] + qrc);
                uint2 pk = { pk2bf(p0, p1), pk2bf(p2, p3) };
                *(uint2*)&Plds[iloc][fc * 16 + g * 4] = pk;
                tsum += (p0 + p1) + (p2 + p3);
            }
            lpart += tsum;
            if (dt < 0) pe0p += tsum; else pe128p += tsum;
        } else if (dt == 0) {
#pragma unroll
            for (int fc = 0; fc < 4; ++fc) {
                const int c0 = relb + fc * 16 + M_;
                float pe[4];
#pragma unroll
                for (int reg = 0; reg < 4; ++reg) {
                    pe[reg] = exp2f(s[fc][reg] + bf2f(QRs[iloc][c0 + reg]));
                    lpart += pe[reg];
                }
                uint2 pk = { pk2bf(pe[0], pe[1]), pk2bf(pe[2], pe[3]) };
                *(uint2*)&Plds[iloc][fc * 16 + g * 4] = pk;
                Wsum[iloc][c0 + 0] = (unsigned short)(pk.x & 0xffffu);
                Wsum[iloc][c0 + 1] = (unsigned short)(pk.x >> 16);
                Wsum[iloc][c0 + 2] = (unsigned short)(pk.y & 0xffffu);
                Wsum[iloc][c0 + 3] = (unsigned short)(pk.y >> 16);
            }
        } else {
#pragma unroll
            for (int fc = 0; fc < 4; ++fc) {
                float pe[4];
#pragma unroll
                for (int reg = 0; reg < 4; ++reg) {
                    const int colr = relb + fc * 16 + reg + M_;
                    const int col  = colr < 0 ? 0 : (colr > 128 ? 128 : colr);
                    pe[reg] = exp2f(s[fc][reg] + bf2f(QRs[iloc][col]));
                    lpart += pe[reg];
                    if (col == 0)        pe0p   += pe[reg];
                    else if (col == 128) pe128p += pe[reg];
                    else                 Wsum[iloc][col] = f2bf(pe[reg]);
                }
                uint2 pk = { pk2bf(pe[0], pe[1]), pk2bf(pe[2], pe[3]) };
                *(uint2*)&Plds[iloc][fc * 16 + g * 4] = pk;
            }
        }

        asm volatile("s_waitcnt lgkmcnt(0)" ::: "memory");
        __builtin_amdgcn_sched_barrier(0);

        // ---- PV (V^T already in regs) ----
        bf16x8 pa0 = *(const bf16x8*)&Plds[iloc][g * 8];
        bf16x8 pa1 = *(const bf16x8*)&Plds[iloc][32 + g * 8];
        __builtin_amdgcn_s_setprio(1);
#pragma unroll
        for (int fd = 0; fd < 4; ++fd) {
            oacc[fd] = __builtin_amdgcn_mfma_f32_16x16x32_bf16(pa0, vv0[fd], oacc[fd], 0, 0, 0);
            oacc[fd] = __builtin_amdgcn_mfma_f32_16x16x32_bf16(pa1, vv1[fd], oacc[fd], 0, 0, 0);
        }
        __builtin_amdgcn_s_setprio(0);

        if (pre) write_vt(Vt[bb ^ 1], jp, d0v, va, vb2);
        asm volatile("s_waitcnt vmcnt(0)" ::: "memory");
        __syncthreads();
        bb ^= 1;
    }

    // ---- finalize row partials ----
    lpart  += __shfl_xor(lpart, 16);  lpart  += __shfl_xor(lpart, 32);
    pe0p   += __shfl_xor(pe0p, 16);   pe0p   += __shfl_xor(pe0p, 32);
    pe128p += __shfl_xor(pe128p, 16); pe128p += __shfl_xor(pe128p, 32);
    if (g == 0) {
        Wsum[iloc][0]   = f2bf(pe0p);
        Wsum[iloc][128] = f2bf(pe128p);
    }
    asm volatile("s_waitcnt lgkmcnt(0)" ::: "memory");
    __builtin_amdgcn_sched_barrier(0);

    // ---- o += wsum @ relv ----
#pragma unroll
    for (int kc = 0; kc < 4; ++kc) {
        bf16x8 wa = *(const bf16x8*)&Wsum[iloc][kc * 32 + g * 8];
#pragma unroll
        for (int fd = 0; fd < 4; ++fd) {
            bf16x8 rv = *(const bf16x8*)&relvT[(size_t)(fd * 16 + fr) * 136 + kc * 32 + g * 8];
            oacc[fd] = __builtin_amdgcn_mfma_f32_16x16x32_bf16(wa, rv, oacc[fd], 0, 0, 0);
        }
    }

    float invd[4], pr128[4];
#pragma unroll
    for (int reg = 0; reg < 4; ++reg) {
        const int src = (lane & 48) | (g * 4 + reg);
        invd[reg]  = 1.f / __shfl(lpart, src, 64);
        pr128[reg] = __shfl(pe128p, src, 64);
    }

#pragma unroll
    for (int fd = 0; fd < 4; ++fd) {
        const float r128 = relv[128 * 64 + fd * 16 + fr];
        unsigned short* op = Ob + head + (size_t)(i0 + w * 16 + g * 4) * D_ + fd * 16 + fr;
#pragma unroll
        for (int reg = 0; reg < 4; ++reg)
            op[(size_t)reg * D_] = f2bf((oacc[fd][reg] + pr128[reg] * r128) * invd[reg]);
    }
}

// ------------------------------------------------------------------
extern "C" void kernel_launch(void* const* d_in, const int* in_sizes, int n_in,
                              void* d_out, int out_size, void* d_ws, size_t ws_size,
                              hipStream_t stream)
{
    const float* x    = (const float*)d_in[0];
    const float* Wq   = (const float*)d_in[1];
    const float* Wk   = (const float*)d_in[2];
    const float* Wv   = (const float*)d_in[3];
    const float* Wo   = (const float*)d_in[4];
    const float* relk = (const float*)d_in[5];
    const float* relv = (const float*)d_in[6];
    float* out = (float*)d_out;

    unsigned short* xb    = (unsigned short*)d_ws;
    unsigned short* Wt    = xb + NLD;
    unsigned short* relkb = Wt + 4 * DD;
    unsigned short* relvT = relkb + 144 * 64;
    unsigned short* QKVb  = relvT + 64 * 136;
    unsigned short* Ob    = QKVb + 3 * NLD;

    prep<<<dim3(6180), 256, 0, stream>>>(x, Wq, Wk, Wv, Wo, relk, relv, xb, Wt, relkb, relvT);

    gemm64<<<dim3(24, 32), 256, 0, stream>>>(xb, Wt, QKVb, nullptr, QSCALE);   // Q,K,V fused

    attn_mfma<<<dim3(512), 256, 0, stream>>>(QKVb, QKVb + NLD, QKVb + 2 * NLD,
                                             relkb, relvT, relv, Ob);

    gemm64<<<dim3(8, 32), 256, 0, stream>>>(Ob, Wt + 3 * DD, nullptr, out, 1.f);
}

// Round 8
// 81.705 us; speedup vs baseline: 8.4447x; 1.0090x over previous
//
#include <hip/hip_runtime.h>
#include <hip/hip_bf16.h>
#include <math.h>

#define B_ 2
#define L_ 1024
#define D_ 1024
#define H_ 16
#define DH_ 64
#define M_ 64
#define R_ 129
#define NLD ((size_t)B_ * L_ * D_)          // 2,097,152
#define DD  ((size_t)D_ * D_)
#define QSCALE 0.18033688011112042f         // DH^-0.5 * log2(e)

using bf16x8 = __attribute__((ext_vector_type(8))) short;
using f32x4  = __attribute__((ext_vector_type(4))) float;

__device__ __forceinline__ unsigned short f2bf(float f) {
    unsigned int x = __builtin_bit_cast(unsigned int, f);
    unsigned int r = x + 0x7fffu + ((x >> 16) & 1u);   // RNE
    return (unsigned short)(r >> 16);
}
__device__ __forceinline__ float bf2f(unsigned short u) {
    unsigned int x = ((unsigned int)u) << 16;
    return __builtin_bit_cast(float, x);
}
__device__ __forceinline__ unsigned int pk2bf(float lo, float hi) {
    __hip_bfloat162 h = __float22bfloat162_rn(float2{lo, hi});  // v_cvt_pk_bf16_f32 (RNE)
    unsigned int u;
    __builtin_memcpy(&u, &h, 4);
    return u;
}

// ------------------------------------------------------------------
// prep: [0,2048) x->bf16 | [2048,6144) W transposes | [6144,6180) rel tables
// ------------------------------------------------------------------
__global__ __launch_bounds__(256)
void prep(const float* __restrict__ x,
          const float* __restrict__ W0, const float* __restrict__ W1,
          const float* __restrict__ W2, const float* __restrict__ W3,
          const float* __restrict__ relk, const float* __restrict__ relv,
          unsigned short* __restrict__ xb, unsigned short* __restrict__ Wt,
          unsigned short* __restrict__ relkb, unsigned short* __restrict__ relvT)
{
    __shared__ float tile[32][33];
    const int bid = blockIdx.x, t = threadIdx.x;
    if (bid < 2048) {
        const int i = bid * 256 + t;
        float4 v = ((const float4*)x)[i];
        short4 o = { (short)f2bf(v.x), (short)f2bf(v.y), (short)f2bf(v.z), (short)f2bf(v.w) };
        ((short4*)xb)[i] = o;
    } else if (bid < 6144) {
        const int wb = bid - 2048;
        const int z = wb >> 10, rem = wb & 1023;
        const float* W = z == 0 ? W0 : z == 1 ? W1 : z == 2 ? W2 : W3;
        unsigned short* T = Wt + (size_t)z * DD;
        const int k0 = (rem >> 5) * 32, n0 = (rem & 31) * 32;
        const int r = t >> 3, c = (t & 7) * 4;
        float4 v = *(const float4*)&W[(size_t)(k0 + r) * D_ + n0 + c];
        tile[r][c] = v.x; tile[r][c + 1] = v.y; tile[r][c + 2] = v.z; tile[r][c + 3] = v.w;
        __syncthreads();
        short4 o = { (short)f2bf(tile[c][r]),     (short)f2bf(tile[c + 1][r]),
                     (short)f2bf(tile[c + 2][r]), (short)f2bf(tile[c + 3][r]) };
        *(short4*)&T[(size_t)(n0 + r) * D_ + k0 + c] = o;
    } else {
        const int idx = (bid - 6144) * 256 + t;
        if (idx < 144 * 64) {
            const int r = idx >> 6, d = idx & 63;
            relkb[idx] = (r < R_) ? f2bf(relk[r * 64 + d]) : (unsigned short)0;
        }
        if (idx < 64 * 136) {
            const int d = idx / 136, r = idx - d * 136;
            relvT[idx] = (r < R_) ? f2bf(relv[r * 64 + d]) : (unsigned short)0;
        }
    }
}

// ------------------------------------------------------------------
// 64(M)x128(N)-tile bf16 MFMA GEMM, BK=64, 4 waves x 32x64. (unchanged R7)
// ------------------------------------------------------------------
__global__ __launch_bounds__(256)
void gemm64(const unsigned short* __restrict__ A, const unsigned short* __restrict__ Bt,
            unsigned short* __restrict__ Cb, float* __restrict__ Cf, float scale0)
{
    __shared__ unsigned short As[64][64];
    __shared__ unsigned short Bs[128][64];

    const int t = threadIdx.x, lane = t & 63, wid = t >> 6;
    const int fr = lane & 15, g = lane >> 4;
    const int m0 = blockIdx.y * 64;
    const int nglob = blockIdx.x * 128;
    const int mat = nglob >> 10;
    const int n0 = nglob & 1023;
    const float scale = (mat == 0) ? scale0 : 1.f;
    const int wm = (wid >> 1) * 32, wn = (wid & 1) * 64;

    f32x4 acc[2][4] = {};

    int arow[2], akof[2], adst[2];
#pragma unroll
    for (int c = 0; c < 2; ++c) {
        const int chunk = c * 256 + t;
        arow[c] = chunk >> 3;
        akof[c] = ((chunk & 7) ^ (arow[c] & 7)) * 8;
        adst[c] = chunk * 8;
    }
    int brow[4], bkof[4], bdst[4];
#pragma unroll
    for (int c = 0; c < 4; ++c) {
        const int chunk = c * 256 + t;
        brow[c] = chunk >> 3;
        bkof[c] = ((chunk & 7) ^ (brow[c] & 7)) * 8;
        bdst[c] = chunk * 8;
    }

    const unsigned short* Abase = A  + (size_t)m0 * D_;
    const unsigned short* Bbase = Bt + (size_t)nglob * D_;

    for (int k0 = 0; k0 < D_; k0 += 64) {
        __syncthreads();
#pragma unroll
        for (int c = 0; c < 2; ++c)
            __builtin_amdgcn_global_load_lds(
                (const __attribute__((address_space(1))) void*)(Abase + (size_t)arow[c] * D_ + k0 + akof[c]),
                (__attribute__((address_space(3))) void*)(&As[0][0] + adst[c]), 16, 0, 0);
#pragma unroll
        for (int c = 0; c < 4; ++c)
            __builtin_amdgcn_global_load_lds(
                (const __attribute__((address_space(1))) void*)(Bbase + (size_t)brow[c] * D_ + k0 + bkof[c]),
                (__attribute__((address_space(3))) void*)(&Bs[0][0] + bdst[c]), 16, 0, 0);
        __syncthreads();

#pragma unroll
        for (int kb = 0; kb < 2; ++kb) {
            bf16x8 av[2], bv[4];
#pragma unroll
            for (int i = 0; i < 2; ++i) {
                const int ra = wm + i * 16 + fr;
                av[i] = *(const bf16x8*)&As[ra][(((kb << 2) + g) ^ (ra & 7)) * 8];
            }
#pragma unroll
            for (int j = 0; j < 4; ++j) {
                const int rb = wn + j * 16 + fr;
                bv[j] = *(const bf16x8*)&Bs[rb][(((kb << 2) + g) ^ (rb & 7)) * 8];
            }
#pragma unroll
            for (int i = 0; i < 2; ++i)
#pragma unroll
                for (int j = 0; j < 4; ++j)
                    acc[i][j] = __builtin_amdgcn_mfma_f32_16x16x32_bf16(av[i], bv[j], acc[i][j], 0, 0, 0);
        }
    }

    const int orow = g * 4;
    if (Cb) {
        unsigned short* Cp = Cb + (size_t)mat * NLD;
#pragma unroll
        for (int i = 0; i < 2; ++i)
#pragma unroll
            for (int j = 0; j < 4; ++j) {
                unsigned short* cp = Cp + (size_t)(m0 + wm + i * 16 + orow) * D_ + n0 + wn + j * 16 + fr;
#pragma unroll
                for (int rg = 0; rg < 4; ++rg)
                    cp[(size_t)rg * D_] = f2bf(acc[i][j][rg] * scale);
            }
    } else {
#pragma unroll
        for (int i = 0; i < 2; ++i)
#pragma unroll
            for (int j = 0; j < 4; ++j) {
                float* cp = Cf + (size_t)(m0 + wm + i * 16 + orow) * D_ + n0 + wn + j * 16 + fr;
#pragma unroll
                for (int rg = 0; rg < 4; ++rg)
                    cp[(size_t)rg * D_] = acc[i][j][rg] * scale;
            }
    }
}

// ------------------------------------------------------------------
// MFMA flash attention. LDS diet: QR+Wsum merged into QW (each interior
// rel-col read-then-overwritten exactly once); Vt single-buffered (reads
// hoisted to regs; raw lgkm-barrier before overwrite). 50 KB -> 3 blk/CU.
// ------------------------------------------------------------------
__device__ __forceinline__ void stage_k(const unsigned short* src, unsigned short* dst, int t)
{
#pragma unroll
    for (int it = 0; it < 2; ++it) {
        const int c = it * 256 + t;
        const int j = c >> 3;
        const int sc = (c & 7) ^ (j & 7);
        __builtin_amdgcn_global_load_lds(
            (const __attribute__((address_space(1))) void*)(src + (size_t)j * D_ + sc * 8),
            (__attribute__((address_space(3))) void*)(dst + c * 8), 16, 0, 0);
    }
}

__device__ __forceinline__ void write_vt(unsigned short (*Vtl)[64], int jp, int d0, bf16x8 a, bf16x8 b)
{
    const int jlo = (2 * jp) & 7;
    const int jc  = jp >> 2;
#pragma unroll
    for (int e = 0; e < 8; ++e) {
        const int d = d0 + e;
        const unsigned int val = (unsigned int)(unsigned short)a[e]
                               | ((unsigned int)(unsigned short)b[e] << 16);
        *(unsigned int*)&Vtl[d][((jc ^ (d & 7)) << 3) + jlo] = val;
    }
}

__global__ __launch_bounds__(256)
void attn_mfma(const unsigned short* __restrict__ Qb, const unsigned short* __restrict__ Kb,
               const unsigned short* __restrict__ Vb,
               const unsigned short* __restrict__ relkb,   // [144][64] bf16
               const unsigned short* __restrict__ relvT,   // [64][136] bf16
               const float* __restrict__ relv,             // [129][64] f32
               unsigned short* __restrict__ Ob)
{
    __shared__ unsigned short Klds[2][64][64];   // 16 KB (dbuf, DMA)
    __shared__ unsigned short Vt[64][64];        // 8 KB (single, reg-staged)
    __shared__ unsigned short Plds[64][72];      // 9 KB
    __shared__ unsigned short QW[64][136];       // 17 KB (QR -> wsum in place)

    const int t    = threadIdx.x;
    const int lane = t & 63;
    const int w    = t >> 6;
    const int fr   = lane & 15;
    const int g    = lane >> 4;

    const int bx  = blockIdx.x;
    const int xcd = bx & 7, slot = bx >> 3;
    const int bh  = (xcd << 2) | (slot >> 4);
    const int rb  = slot & 15;
    const int b   = bh >> 4, h = bh & 15;
    const int i0  = rb * 64;
    const size_t head = (size_t)b * L_ * D_ + (size_t)h * DH_;

    const int iloc = w * 16 + fr;

    const unsigned short* Kh = Kb + head;
    const unsigned short* Vh = Vb + head;

    stage_k(Kh, &Klds[0][0][0], t);

    const int jp = t & 31, d0v = ((t >> 5) & 7) * 8;
    bf16x8 va  = *(const bf16x8*)(Vh + (size_t)(2 * jp) * D_ + d0v);
    bf16x8 vb2 = *(const bf16x8*)(Vh + (size_t)(2 * jp + 1) * D_ + d0v);

    bf16x8 qf[2];
    {
        const unsigned short* qp = Qb + head + (size_t)(i0 + iloc) * D_;
        qf[0] = *(const bf16x8*)(qp + g * 8);
        qf[1] = *(const bf16x8*)(qp + 32 + g * 8);
    }

    // QR^T = relk @ q^T  -> QW cols 0..128 (per-row bias table)
#pragma unroll
    for (int rc = 0; rc < 9; ++rc) {
        f32x4 acc = {};
#pragma unroll
        for (int kb = 0; kb < 2; ++kb) {
            bf16x8 rv = *(const bf16x8*)&relkb[(size_t)(rc * 16 + fr) * 64 + kb * 32 + g * 8];
            acc = __builtin_amdgcn_mfma_f32_16x16x32_bf16(rv, qf[kb], acc, 0, 0, 0);
        }
        if (rc < 8) {
            uint2 pk = { pk2bf(acc[0], acc[1]), pk2bf(acc[2], acc[3]) };
            *(uint2*)&QW[iloc][rc * 16 + g * 4] = pk;
        } else if (g == 0) {
            QW[iloc][128] = f2bf(acc[0]);
        }
    }
    // boundary blocks: zero interior cols that no tile will overwrite
    if (rb == 0) {
        for (int c = 1 + g; c <= 63 - iloc; c += 4) QW[iloc][c] = 0;
    } else if (rb == 15) {
        for (int c = 128 - iloc + g; c <= 127; c += 4) QW[iloc][c] = 0;
    }

    write_vt(Vt, jp, d0v, va, vb2);
    asm volatile("s_waitcnt vmcnt(0)" ::: "memory");
    __syncthreads();

    const float qr0   = bf2f(QW[iloc][0]);
    const float qr128 = bf2f(QW[iloc][128]);

    f32x4 oacc[4] = {};
    float lpart = 0.f, pe0p = 0.f, pe128p = 0.f;

    int bb = 0;
    for (int jt = 0; jt < 16; ++jt) {
        const bool pre = (jt < 15);
        if (pre) {
            stage_k(Kh + (size_t)(jt + 1) * 64 * D_, &Klds[bb ^ 1][0][0], t);
            const unsigned short* vp = Vh + (size_t)((jt + 1) * 64 + 2 * jp) * D_ + d0v;
            va  = *(const bf16x8*)vp;
            vb2 = *(const bf16x8*)(vp + D_);
        }

        // ---- S^T = K @ Q^T ----
        f32x4 s[4];
        __builtin_amdgcn_s_setprio(1);
#pragma unroll
        for (int fc = 0; fc < 4; ++fc) {
            f32x4 a = {};
            const int j = fc * 16 + fr;
#pragma unroll
            for (int kb = 0; kb < 2; ++kb) {
                bf16x8 kv = *(const bf16x8*)&Klds[bb][j][(((kb << 2) + g) ^ (j & 7)) * 8];
                a = __builtin_amdgcn_mfma_f32_16x16x32_bf16(kv, qf[kb], a, 0, 0, 0);
            }
            s[fc] = a;
        }
        __builtin_amdgcn_s_setprio(0);

        // ---- V^T fragments to regs (single Vt buffer; current tile) ----
        bf16x8 vv0[4], vv1[4];
#pragma unroll
        for (int fd = 0; fd < 4; ++fd) {
            const int d = fd * 16 + fr;
            vv0[fd] = *(const bf16x8*)&Vt[d][((g)     ^ (d & 7)) * 8];
            vv1[fd] = *(const bf16x8*)&Vt[d][((4 + g) ^ (d & 7)) * 8];
        }

        const int dt   = (jt - rb) * 64;
        const int relb = dt - iloc + g * 4;

        if (dt <= -128 || dt >= 128) {
            const float qrc = (dt < 0) ? qr0 : qr128;
            float tsum = 0.f;
#pragma unroll
            for (int fc = 0; fc < 4; ++fc) {
                float p0 = exp2f(s[fc][0] + qrc);
                float p1 = exp2f(s[fc][1] + qrc);
                float p2 = exp2f(s[fc][2] + qrc);
                float p3 = exp2f(s[fc][3] + qrc);
                uint2 pk = { pk2bf(p0, p1), pk2bf(p2, p3) };
                *(uint2*)&Plds[iloc][fc * 16 + g * 4] = pk;
                tsum += (p0 + p1) + (p2 + p3);
            }
            lpart += tsum;
            if (dt < 0) pe0p += tsum; else pe128p += tsum;
        } else if (dt == 0) {
            // interior: read bias col, overwrite same col with weight
#pragma unroll
            for (int fc = 0; fc < 4; ++fc) {
                const int c0 = relb + fc * 16 + M_;
                float pe[4];
#pragma unroll
                for (int reg = 0; reg < 4; ++reg) {
                    pe[reg] = exp2f(s[fc][reg] + bf2f(QW[iloc][c0 + reg]));
                    lpart += pe[reg];
                }
                uint2 pk = { pk2bf(pe[0], pe[1]), pk2bf(pe[2], pe[3]) };
                *(uint2*)&Plds[iloc][fc * 16 + g * 4] = pk;
                QW[iloc][c0 + 0] = (unsigned short)(pk.x & 0xffffu);
                QW[iloc][c0 + 1] = (unsigned short)(pk.x >> 16);
                QW[iloc][c0 + 2] = (unsigned short)(pk.y & 0xffffu);
                QW[iloc][c0 + 3] = (unsigned short)(pk.y >> 16);
            }
        } else {
            // edge (dt = ±64): clamped col; interior slots overwritten in place
#pragma unroll
            for (int fc = 0; fc < 4; ++fc) {
                float pe[4];
#pragma unroll
                for (int reg = 0; reg < 4; ++reg) {
                    const int colr = relb + fc * 16 + reg + M_;
                    const int col  = colr < 0 ? 0 : (colr > 128 ? 128 : colr);
                    pe[reg] = exp2f(s[fc][reg] + bf2f(QW[iloc][col]));
                    lpart += pe[reg];
                    if (col == 0)        pe0p   += pe[reg];
                    else if (col == 128) pe128p += pe[reg];
                    else                 QW[iloc][col] = f2bf(pe[reg]);
                }
                uint2 pk = { pk2bf(pe[0], pe[1]), pk2bf(pe[2], pe[3]) };
                *(uint2*)&Plds[iloc][fc * 16 + g * 4] = pk;
            }
        }

        asm volatile("s_waitcnt lgkmcnt(0)" ::: "memory");
        __builtin_amdgcn_sched_barrier(0);

        // ---- PV (V^T in regs, P rows via LDS) ----
        bf16x8 pa0 = *(const bf16x8*)&Plds[iloc][g * 8];
        bf16x8 pa1 = *(const bf16x8*)&Plds[iloc][32 + g * 8];
        __builtin_amdgcn_s_setprio(1);
#pragma unroll
        for (int fd = 0; fd < 4; ++fd) {
            oacc[fd] = __builtin_amdgcn_mfma_f32_16x16x32_bf16(pa0, vv0[fd], oacc[fd], 0, 0, 0);
            oacc[fd] = __builtin_amdgcn_mfma_f32_16x16x32_bf16(pa1, vv1[fd], oacc[fd], 0, 0, 0);
        }
        __builtin_amdgcn_s_setprio(0);

        if (pre) {
            // all waves must finish their Vt reg-reads before overwrite;
            // raw barrier (keep K-DMA vmcnt in flight)
            asm volatile("s_waitcnt lgkmcnt(0)" ::: "memory");
            __builtin_amdgcn_s_barrier();
            write_vt(Vt, jp, d0v, va, vb2);
        }
        asm volatile("s_waitcnt vmcnt(0)" ::: "memory");
        __syncthreads();
        bb ^= 1;
    }

    // ---- finalize row partials ----
    lpart  += __shfl_xor(lpart, 16);  lpart  += __shfl_xor(lpart, 32);
    pe0p   += __shfl_xor(pe0p, 16);   pe0p   += __shfl_xor(pe0p, 32);
    pe128p += __shfl_xor(pe128p, 16); pe128p += __shfl_xor(pe128p, 32);
    if (g == 0) {
        QW[iloc][0]   = f2bf(pe0p);
        QW[iloc][128] = f2bf(pe128p);
    }
    asm volatile("s_waitcnt lgkmcnt(0)" ::: "memory");
    __builtin_amdgcn_sched_barrier(0);

    // ---- o += wsum @ relv (cols 0..127 via MFMA; col 128 scalar) ----
#pragma unroll
    for (int kc = 0; kc < 4; ++kc) {
        bf16x8 wa = *(const bf16x8*)&QW[iloc][kc * 32 + g * 8];
#pragma unroll
        for (int fd = 0; fd < 4; ++fd) {
            bf16x8 rv = *(const bf16x8*)&relvT[(size_t)(fd * 16 + fr) * 136 + kc * 32 + g * 8];
            oacc[fd] = __builtin_amdgcn_mfma_f32_16x16x32_bf16(wa, rv, oacc[fd], 0, 0, 0);
        }
    }

    float invd[4], pr128[4];
#pragma unroll
    for (int reg = 0; reg < 4; ++reg) {
        const int src = (lane & 48) | (g * 4 + reg);
        invd[reg]  = 1.f / __shfl(lpart, src, 64);
        pr128[reg] = __shfl(pe128p, src, 64);
    }

#pragma unroll
    for (int fd = 0; fd < 4; ++fd) {
        const float r128 = relv[128 * 64 + fd * 16 + fr];
        unsigned short* op = Ob + head + (size_t)(i0 + w * 16 + g * 4) * D_ + fd * 16 + fr;
#pragma unroll
        for (int reg = 0; reg < 4; ++reg)
            op[(size_t)reg * D_] = f2bf((oacc[fd][reg] + pr128[reg] * r128) * invd[reg]);
    }
}

// ------------------------------------------------------------------
extern "C" void kernel_launch(void* const* d_in, const int* in_sizes, int n_in,
                              void* d_out, int out_size, void* d_ws, size_t ws_size,
                              hipStream_t stream)
{
    const float* x    = (const float*)d_in[0];
    const float* Wq   = (const float*)d_in[1];
    const float* Wk   = (const float*)d_in[2];
    const float* Wv   = (const float*)d_in[3];
    const float* Wo   = (const float*)d_in[4];
    const float* relk = (const float*)d_in[5];
    const float* relv = (const float*)d_in[6];
    float* out = (float*)d_out;

    unsigned short* xb    = (unsigned short*)d_ws;
    unsigned short* Wt    = xb + NLD;
    unsigned short* relkb = Wt + 4 * DD;
    unsigned short* relvT = relkb + 144 * 64;
    unsigned short* QKVb  = relvT + 64 * 136;
    unsigned short* Ob    = QKVb + 3 * NLD;

    prep<<<dim3(6180), 256, 0, stream>>>(x, Wq, Wk, Wv, Wo, relk, relv, xb, Wt, relkb, relvT);

    gemm64<<<dim3(24, 32), 256, 0, stream>>>(xb, Wt, QKVb, nullptr, QSCALE);   // Q,K,V fused

    attn_mfma<<<dim3(512), 256, 0, stream>>>(QKVb, QKVb + NLD, QKVb + 2 * NLD,
                                             relkb, relvT, relv, Ob);

    gemm64<<<dim3(8, 32), 256, 0, stream>>>(Ob, Wt + 3 * DD, nullptr, out, 1.f);
}